// Round 21
// baseline (447.580 us; speedup 1.0000x reference)
//
#include <hip/hip_runtime.h>
#include <hip/hip_bf16.h>

typedef __attribute__((ext_vector_type(8))) short short8_t;
typedef __attribute__((ext_vector_type(4))) float f32x4;

__device__ __forceinline__ float bf2f(unsigned short u) {
    return __uint_as_float(((unsigned)u) << 16);
}
__device__ __forceinline__ unsigned short f2bf(float f) {
    __hip_bfloat16 h = __float2bfloat16(f);
    return *reinterpret_cast<unsigned short*>(&h);
}

// exact-GELU via Abramowitz-Stegun 7.1.26 erf (|err| <= 1.5e-7), branch-free.
__device__ __forceinline__ float fast_gelu(float v) {
    float ax = fabsf(v) * 0.70710678118f;
    float t  = __builtin_amdgcn_rcpf(1.f + 0.3275911f * ax);
    float poly = t * (0.254829592f + t * (-0.284496736f + t * (1.421413741f
               + t * (-1.453152027f + t * 1.061405429f))));
    float e  = __expf(-ax * ax);
    float er = 1.f - poly * e;                 // erf(ax), ax >= 0
    float s  = (v >= 0.f) ? er : -er;
    return 0.5f * v * (1.f + s);
}

// async global->LDS, 16B per lane; LDS dest = wave-uniform base + lane*16
__device__ __forceinline__ void async16(const unsigned short* g, unsigned short* l) {
    __builtin_amdgcn_global_load_lds(
        (const __attribute__((address_space(1))) unsigned int*)g,
        (__attribute__((address_space(3))) unsigned int*)l,
        16, 0, 0);
}

// window-order row r (r = wb*49 + n) -> natural token index
__device__ __forceinline__ int win_row_to_token(int r) {
    int wb = r / 49, n = r - wb * 49;
    int wq = wb & 7, hb = (wb >> 3) & 7, d = (wb >> 6) & 7, b = wb >> 9;
    int hh = n / 7, ww2 = n - hh * 7;
    return ((b * 8 + d) * 56 + hb * 7 + hh) * 56 + wq * 7 + ww2;
}

// ---------------- f32 -> bf16 bulk convert ----------------
__global__ __launch_bounds__(256) void conv_kernel(
    const float* __restrict__ src, unsigned short* __restrict__ dst, int n4)
{
    int stride = gridDim.x * 256;
    for (int i = blockIdx.x * 256 + threadIdx.x; i < n4; i += stride) {
        float4 v = *reinterpret_cast<const float4*>(&src[(size_t)i * 4]);
        short4 o;
        o.x = (short)f2bf(v.x); o.y = (short)f2bf(v.y);
        o.z = (short)f2bf(v.z); o.w = (short)f2bf(v.w);
        *reinterpret_cast<short4*>(&dst[(size_t)i * 4]) = o;
    }
}

// 4 weight tensors in one dispatch (vec4 counts)
__global__ __launch_bounds__(256) void conv4_kernel(
    const float* __restrict__ s0, unsigned short* __restrict__ d0, int n0,
    const float* __restrict__ s1, unsigned short* __restrict__ d1, int n1,
    const float* __restrict__ s2, unsigned short* __restrict__ d2, int n2,
    const float* __restrict__ s3, unsigned short* __restrict__ d3, int n3)
{
    int stride = gridDim.x * 256;
    int total = n0 + n1 + n2 + n3;
    for (int i = blockIdx.x * 256 + threadIdx.x; i < total; i += stride) {
        const float* s; unsigned short* d; int j = i;
        if (j < n0) { s = s0; d = d0; }
        else if ((j -= n0) < n1) { s = s1; d = d1; }
        else if ((j -= n1) < n2) { s = s2; d = d2; }
        else { j -= n2; s = s3; d = d3; }
        float4 v = *reinterpret_cast<const float4*>(&s[(size_t)j * 4]);
        short4 o;
        o.x = (short)f2bf(v.x); o.y = (short)f2bf(v.y);
        o.z = (short)f2bf(v.z); o.w = (short)f2bf(v.w);
        *reinterpret_cast<short4*>(&d[(size_t)j * 4]) = o;
    }
}

// ---------------- prep stage 1: CPB-MLP table, one block per table row ----------------
__global__ __launch_bounds__(256) void prep_table_kernel(
    const float* __restrict__ w1, const float* __restrict__ b1,
    const float* __restrict__ w2, const float* __restrict__ tabin,
    float* __restrict__ tableg)
{
    const int i = blockIdx.x;          // 0..168
    const int t = threadIdx.x;
    const float c0 = tabin[i * 3], c1 = tabin[i * 3 + 1], c2 = tabin[i * 3 + 2];
    float part[8] = {0.f, 0.f, 0.f, 0.f, 0.f, 0.f, 0.f, 0.f};
    for (int j = t; j < 512; j += 256) {
        float hv = fmaxf(c0 * w1[j * 3] + c1 * w1[j * 3 + 1] + c2 * w1[j * 3 + 2] + b1[j], 0.f);
        #pragma unroll
        for (int h = 0; h < 8; ++h) part[h] += hv * w2[h * 512 + j];
    }
    #pragma unroll
    for (int h = 0; h < 8; ++h) {
        float v = part[h];
        v += __shfl_xor(v, 1);  v += __shfl_xor(v, 2);  v += __shfl_xor(v, 4);
        v += __shfl_xor(v, 8);  v += __shfl_xor(v, 16); v += __shfl_xor(v, 32);
        part[h] = v;
    }
    __shared__ float red[4][8];
    const int wv = t >> 6, lane = t & 63;
    if (lane == 0) {
        #pragma unroll
        for (int h = 0; h < 8; ++h) red[wv][h] = part[h];
    }
    __syncthreads();
    if (t < 8) tableg[i * 8 + t] = red[0][t] + red[1][t] + red[2][t] + red[3][t];
}

// ---------------- prep stage 2: scales, qkv bias, rpbf expansion ----------------
__global__ __launch_bounds__(256) void prep_expand_kernel(
    const float* __restrict__ logit_scale,
    const float* __restrict__ qb, const float* __restrict__ vb,
    const int* __restrict__ rpi, const float* __restrict__ tableg,
    float* __restrict__ scales, float* __restrict__ rpbf,
    float* __restrict__ qkvb)
{
    const int stride = gridDim.x * 256;
    const int gt = blockIdx.x * 256 + threadIdx.x;
    if (gt < 8) scales[gt] = expf(fminf(logit_scale[gt], 4.6051702f)); // ln(100)
    for (int i = gt; i < 768; i += stride) {
        float o;
        if (i < 256) o = qb[i];
        else if (i < 512) o = 0.f;
        else o = vb[i - 512];
        qkvb[i] = o;
    }
    for (int e = gt; e < 32768; e += stride) {
        int h = e >> 12, rem = e & 4095;
        int mi = rem >> 10, ji = (rem >> 8) & 3;
        int r16 = (rem >> 4) & 15, g4 = (rem >> 2) & 3, r = rem & 3;
        int i = mi * 16 + g4 * 4 + r, j = ji * 16 + r16;
        float val = 0.f;
        if (i < 49 && j < 49) {
            float xv = tableg[rpi[i * 49 + j] * 8 + h];
            val = 16.f / (1.f + expf(-xv));
        }
        rpbf[e] = val;
    }
}

// ---------------- GEMM: 128x128 tile, 8 waves x (64x32), 3-buffer pipeline ----------------
template<int ACT>
__global__ __launch_bounds__(512, 6) void gemm2_kernel(
    const unsigned short* __restrict__ A, const unsigned short* __restrict__ W,
    const float* __restrict__ bias, unsigned short* __restrict__ C,
    int M, int N, int K, int ntn)
{
    __shared__ unsigned short smem[24576];   // 48KB: 3 x (As 128x32 + Bs 128x32)
    const int tid = threadIdx.x;
    const int lane = tid & 63, wv = tid >> 6;
    const int wr = wv >> 2, wc = wv & 3;
    const int nwg = gridDim.x;
    const int virt = (blockIdx.x & 7) * (nwg >> 3) + (blockIdx.x >> 3);
    const int bn = virt % ntn, bm = virt / ntn;
    const size_t arow0 = (size_t)bm * 128;
    const size_t brow0 = (size_t)bn * 128;
    const int r16 = lane & 15, g4 = lane >> 4;
    const int srow_l = lane >> 2;
    const int sgran  = (lane & 3) ^ ((srow_l >> 1) & 3);
    f32x4 acc[4][2] = {};

    auto STAGE = [&](int buf, int kt) {      // 2 loads per thread
        unsigned short* As = smem + buf * 8192;
        unsigned short* Bs = As + 4096;
        int row0 = wv * 16;
        async16(&A[(arow0 + row0 + srow_l) * (size_t)K + kt + sgran * 8], &As[row0 * 32]);
        async16(&W[(brow0 + row0 + srow_l) * (size_t)K + kt + sgran * 8], &Bs[row0 * 32]);
    };
    auto COMPUTE = [&](int buf) {
        unsigned short* As = smem + buf * 8192;
        unsigned short* Bs = As + 4096;
        short8_t af[4], bfr[2];
        const int gsw = g4 ^ ((r16 >> 1) & 3);
        #pragma unroll
        for (int m = 0; m < 4; ++m) {
            int row = wr * 64 + m * 16 + r16;
            af[m] = *reinterpret_cast<const short8_t*>(&As[row * 32 + gsw * 8]);
        }
        #pragma unroll
        for (int n = 0; n < 2; ++n) {
            int row = wc * 32 + n * 16 + r16;
            bfr[n] = *reinterpret_cast<const short8_t*>(&Bs[row * 32 + gsw * 8]);
        }
        #pragma unroll
        for (int m = 0; m < 4; ++m)
            #pragma unroll
            for (int n = 0; n < 2; ++n)
                acc[m][n] = __builtin_amdgcn_mfma_f32_16x16x32_bf16(af[m], bfr[n], acc[m][n], 0, 0, 0);
    };

    const int nk = K >> 5;
    STAGE(0, 0);
    STAGE(1, 32);
    int cb = 0;
    for (int ks = 0; ks < nk; ++ks) {
        if (ks == nk - 1) { asm volatile("s_waitcnt vmcnt(0)" ::: "memory"); }
        else              { asm volatile("s_waitcnt vmcnt(2)" ::: "memory"); }
        __builtin_amdgcn_sched_barrier(0);
        asm volatile("s_barrier" ::: "memory");
        if (ks + 2 < nk) {
            int sb = cb + 2; if (sb >= 3) sb -= 3;
            STAGE(sb, (ks + 2) << 5);
        }
        __builtin_amdgcn_sched_barrier(0);
        COMPUTE(cb);
        cb = (cb == 2) ? 0 : cb + 1;
    }
    __builtin_amdgcn_sched_barrier(0);
    asm volatile("s_barrier" ::: "memory");  // LDS dead; epilogue overlays

    unsigned short* Cs = smem + wv * 2304;   // 64 x 36 ushorts per wave
    const int rbase = g4 * 4;
    const int srow = lane >> 2, scol = (lane & 3) * 8;
    const int gcol0 = bn * 128 + wc * 32;
    #pragma unroll
    for (int n = 0; n < 2; ++n) {
        float bv = bias[gcol0 + n * 16 + r16];
        #pragma unroll
        for (int m = 0; m < 4; ++m)
            #pragma unroll
            for (int r = 0; r < 4; ++r) {
                float v = acc[m][n][r] + bv;
                if (ACT == 1) v = fast_gelu(v);
                Cs[(m * 16 + rbase + r) * 36 + n * 16 + r16] = f2bf(v);
            }
    }
    #pragma unroll
    for (int pass = 0; pass < 4; ++pass) {
        int lr = pass * 16 + srow;
        int grow = bm * 128 + wr * 64 + lr;
        short8_t vv = *reinterpret_cast<const short8_t*>(&Cs[lr * 36 + scol]);
        *reinterpret_cast<short8_t*>(&C[(size_t)grow * N + gcol0 + scol]) = vv;
    }
}

// ---------------- fused GEMM + residual + LayerNorm (N=256), 3-buffer pipeline ----------
template<int SCATTER, int OUT_F32>
__global__ __launch_bounds__(512) void gemm_ln_kernel(
    const unsigned short* __restrict__ A, const unsigned short* __restrict__ W,
    const float* __restrict__ bias, const unsigned short* __restrict__ resid,
    const float* __restrict__ gamma, const float* __restrict__ beta,
    void* __restrict__ Cv, int M, int K)
{
    __shared__ unsigned short smem[36864];   // 72KB, 3 buffers
    const int tid = threadIdx.x;
    const int lane = tid & 63, wv = tid >> 6;
    const int wr = wv >> 2, wc = wv & 3;
    const int nwg = gridDim.x;
    const int bm = (blockIdx.x & 7) * (nwg >> 3) + (blockIdx.x >> 3);
    const size_t arow0 = (size_t)bm * 128;
    const int r16 = lane & 15, g4 = lane >> 4;
    const int srow_l = lane >> 2;
    const int sgran = (lane & 3) ^ ((srow_l >> 1) & 3);
    f32x4 acc[4][4] = {};

    auto STAGE = [&](int buf, int kt) {
        unsigned short* As = smem + buf * 12288;
        unsigned short* Bs = As + 4096;
        async16(&A[(arow0 + wv * 16 + srow_l) * (size_t)K + kt + sgran * 8],
                &As[(wv * 16) * 32]);
        #pragma unroll
        for (int i = 0; i < 2; ++i) {
            int row0 = wv * 32 + i * 16;
            async16(&W[(size_t)(row0 + srow_l) * K + kt + sgran * 8], &Bs[row0 * 32]);
        }
    };
    auto COMPUTE = [&](int buf) {
        unsigned short* As = smem + buf * 12288;
        unsigned short* Bs = As + 4096;
        short8_t af[4], bfr[4];
        const int gsw = g4 ^ ((r16 >> 1) & 3);
        #pragma unroll
        for (int m = 0; m < 4; ++m) {
            int row = wr * 64 + m * 16 + r16;
            af[m] = *reinterpret_cast<const short8_t*>(&As[row * 32 + gsw * 8]);
        }
        #pragma unroll
        for (int n = 0; n < 4; ++n) {
            int row = wc * 64 + n * 16 + r16;
            bfr[n] = *reinterpret_cast<const short8_t*>(&Bs[row * 32 + gsw * 8]);
        }
        #pragma unroll
        for (int m = 0; m < 4; ++m)
            #pragma unroll
            for (int n = 0; n < 4; ++n)
                acc[m][n] = __builtin_amdgcn_mfma_f32_16x16x32_bf16(af[m], bfr[n], acc[m][n], 0, 0, 0);
    };

    const int nk = K >> 5;
    STAGE(0, 0);
    STAGE(1, 32);
    int cb = 0;
    for (int ks = 0; ks < nk; ++ks) {
        if (ks == nk - 1) { asm volatile("s_waitcnt vmcnt(0)" ::: "memory"); }
        else              { asm volatile("s_waitcnt vmcnt(3)" ::: "memory"); }
        __builtin_amdgcn_sched_barrier(0);
        asm volatile("s_barrier" ::: "memory");
        if (ks + 2 < nk) {
            int sb = cb + 2; if (sb >= 3) sb -= 3;
            STAGE(sb, (ks + 2) << 5);
        }
        __builtin_amdgcn_sched_barrier(0);
        COMPUTE(cb);
        cb = (cb == 2) ? 0 : cb + 1;
    }
    __builtin_amdgcn_sched_barrier(0);
    asm volatile("s_barrier" ::: "memory");

    float bv[4];
    #pragma unroll
    for (int n = 0; n < 4; ++n) bv[n] = bias[wc * 64 + n * 16 + r16];
    float* psum  = reinterpret_cast<float*>(smem + 19456);   // [128][4]
    float* psq   = psum + 512;                               // [128][4]
    float* stats = psq + 512;                                // [128][2]
    #pragma unroll
    for (int m = 0; m < 4; ++m) {
        #pragma unroll
        for (int r = 0; r < 4; ++r) {
            float s = 0.f, s2 = 0.f;
            #pragma unroll
            for (int n = 0; n < 4; ++n) {
                float v = acc[m][n][r] + bv[n];
                s += v; s2 += v * v;
            }
            s  += __shfl_xor(s, 1);  s  += __shfl_xor(s, 2);
            s  += __shfl_xor(s, 4);  s  += __shfl_xor(s, 8);
            s2 += __shfl_xor(s2, 1); s2 += __shfl_xor(s2, 2);
            s2 += __shfl_xor(s2, 4); s2 += __shfl_xor(s2, 8);
            if (r16 == 0) {
                int row = wr * 64 + m * 16 + g4 * 4 + r;
                psum[row * 4 + wc] = s;
                psq[row * 4 + wc]  = s2;
            }
        }
    }
    __syncthreads();
    if (tid < 128) {
        f32x4 a = *reinterpret_cast<const f32x4*>(&psum[tid * 4]);
        f32x4 b = *reinterpret_cast<const f32x4*>(&psq[tid * 4]);
        float mu  = (a[0] + a[1] + a[2] + a[3]) * 0.00390625f;
        float ex2 = (b[0] + b[1] + b[2] + b[3]) * 0.00390625f;
        stats[tid * 2]     = mu;
        stats[tid * 2 + 1] = rsqrtf(ex2 - mu * mu + 1e-5f);
    }
    __syncthreads();

    unsigned short* Cs = smem + wv * 2432;
    const int rbase = g4 * 4;
    const int srow = lane >> 3, scol = (lane & 7) * 8;
    const int gcol0 = wc * 64;
    f32x4 gm0 = *reinterpret_cast<const f32x4*>(&gamma[gcol0 + scol]);
    f32x4 gm1 = *reinterpret_cast<const f32x4*>(&gamma[gcol0 + scol + 4]);
    f32x4 bt0 = *reinterpret_cast<const f32x4*>(&beta[gcol0 + scol]);
    f32x4 bt1 = *reinterpret_cast<const f32x4*>(&beta[gcol0 + scol + 4]);
    #pragma unroll
    for (int p = 0; p < 2; ++p) {
        #pragma unroll
        for (int n = 0; n < 4; ++n)
            #pragma unroll
            for (int m2 = 0; m2 < 2; ++m2)
                #pragma unroll
                for (int r = 0; r < 4; ++r)
                    Cs[(m2 * 16 + rbase + r) * 76 + n * 16 + r16] =
                        f2bf(acc[p * 2 + m2][n][r] + bv[n]);
        #pragma unroll
        for (int rr = 0; rr < 4; ++rr) {
            int lr = rr * 8 + srow;
            int lrow = wr * 64 + p * 32 + lr;
            int grow = bm * 128 + lrow;
            size_t orow = SCATTER ? (size_t)win_row_to_token(grow) : (size_t)grow;
            float mu  = stats[lrow * 2];
            float inv = stats[lrow * 2 + 1];
            short8_t cv = *reinterpret_cast<const short8_t*>(&Cs[lr * 76 + scol]);
            short8_t rv = *reinterpret_cast<const short8_t*>(&resid[orow * 256 + gcol0 + scol]);
            float o[8];
            #pragma unroll
            for (int e = 0; e < 8; ++e) {
                float g = (e < 4) ? gm0[e] : gm1[e - 4];
                float bb = (e < 4) ? bt0[e] : bt1[e - 4];
                o[e] = bf2f((unsigned short)rv[e])
                     + (bf2f((unsigned short)cv[e]) - mu) * inv * g + bb;
            }
            if (OUT_F32) {
                float* outp = (float*)Cv + orow * 256 + gcol0 + scol;
                f32x4 o0, o1;
                #pragma unroll
                for (int e = 0; e < 4; ++e) { o0[e] = o[e]; o1[e] = o[e + 4]; }
                *reinterpret_cast<f32x4*>(outp)     = o0;
                *reinterpret_cast<f32x4*>(outp + 4) = o1;
            } else {
                unsigned short* outp = (unsigned short*)Cv + orow * 256 + gcol0 + scol;
                short8_t ov;
                #pragma unroll
                for (int e = 0; e < 8; ++e) ov[e] = (short)f2bf(o[e]);
                *reinterpret_cast<short8_t*>(outp) = ov;
            }
        }
    }
}

// ---------------- fused MLP v2: per 128-row strip, fc1 -> h (L2-hot) -> fc2+LN ----------
// Phase 1: h_strip = gelu(x1@W1^T + b1)  (8 x gemm2-structure pipelines, bn 0..7)
// Phase 2: out = x1 + LN(h_strip@W2^T + b2)  (gemm_ln structure, K=1024, 2-buffer)
// h strip (128x1024 bf16 = 256KB) stays in the block's XCD L2 between phases.
__global__ __launch_bounds__(512) void mlp2_kernel(
    const unsigned short* __restrict__ A,    // x1 [M,256] (also LN residual)
    const unsigned short* __restrict__ W1,   // [1024,256]
    const float* __restrict__ b1,
    unsigned short* __restrict__ H,          // scratch [M,1024]
    const unsigned short* __restrict__ W2,   // [256,1024]
    const float* __restrict__ b2,
    const float* __restrict__ gamma, const float* __restrict__ beta,
    float* __restrict__ out, int M)
{
    __shared__ unsigned short smem[24576];   // 48KB union of both phases
    const int tid = threadIdx.x;
    const int lane = tid & 63, wv = tid >> 6;
    const int wr = wv >> 2, wc = wv & 3;
    const int nwg = gridDim.x;               // 784, %8==0
    const int bm = (blockIdx.x & 7) * (nwg >> 3) + (blockIdx.x >> 3);
    const size_t arow0 = (size_t)bm * 128;
    const int r16 = lane & 15, g4 = lane >> 4;
    const int srow_l = lane >> 2;
    const int sgran = (lane & 3) ^ ((srow_l >> 1) & 3);
    const int gsw = g4 ^ ((r16 >> 1) & 3);

    // ================= Phase 1: fc1 + GELU -> H strip =================
    for (int bn = 0; bn < 8; ++bn) {
        // guard: prior epilogue's Cs ds_reads must finish before buffers are re-staged
        asm volatile("s_waitcnt lgkmcnt(0)" ::: "memory");
        __builtin_amdgcn_sched_barrier(0);
        asm volatile("s_barrier" ::: "memory");

        f32x4 acc[4][2] = {};
        auto STAGE1 = [&](int buf, int kt) {   // 2 loads/thread; buffers at buf*16KB
            unsigned short* As = smem + buf * 8192;
            unsigned short* Bs = As + 4096;
            int row0 = wv * 16;
            async16(&A[(arow0 + row0 + srow_l) * 256 + kt + sgran * 8], &As[row0 * 32]);
            async16(&W1[(size_t)(bn * 128 + row0 + srow_l) * 256 + kt + sgran * 8], &Bs[row0 * 32]);
        };
        auto COMPUTE1 = [&](int buf) {
            unsigned short* As = smem + buf * 8192;
            unsigned short* Bs = As + 4096;
            short8_t af[4], bfr[2];
            #pragma unroll
            for (int m = 0; m < 4; ++m) {
                int row = wr * 64 + m * 16 + r16;
                af[m] = *reinterpret_cast<const short8_t*>(&As[row * 32 + gsw * 8]);
            }
            #pragma unroll
            for (int n = 0; n < 2; ++n) {
                int row = wc * 32 + n * 16 + r16;
                bfr[n] = *reinterpret_cast<const short8_t*>(&Bs[row * 32 + gsw * 8]);
            }
            #pragma unroll
            for (int m = 0; m < 4; ++m)
                #pragma unroll
                for (int n = 0; n < 2; ++n)
                    acc[m][n] = __builtin_amdgcn_mfma_f32_16x16x32_bf16(af[m], bfr[n], acc[m][n], 0, 0, 0);
        };

        STAGE1(0, 0);
        STAGE1(1, 32);
        int cb = 0;
        for (int ks = 0; ks < 8; ++ks) {
            if (ks == 7) { asm volatile("s_waitcnt vmcnt(0)" ::: "memory"); }
            else         { asm volatile("s_waitcnt vmcnt(2)" ::: "memory"); }
            __builtin_amdgcn_sched_barrier(0);
            asm volatile("s_barrier" ::: "memory");
            if (ks + 2 < 8) {
                int sb = cb + 2; if (sb >= 3) sb -= 3;
                STAGE1(sb, (ks + 2) << 5);
            }
            __builtin_amdgcn_sched_barrier(0);
            COMPUTE1(cb);
            cb = (cb == 2) ? 0 : cb + 1;
        }
        __builtin_amdgcn_sched_barrier(0);
        asm volatile("s_barrier" ::: "memory");   // pipeline dead; epilogue overlays

        unsigned short* Cs = smem + wv * 2304;    // 64 x 36 per wave
        const int rbase = g4 * 4;
        const int srow = lane >> 2, scol = (lane & 3) * 8;
        const int gcol0 = bn * 128 + wc * 32;
        #pragma unroll
        for (int n = 0; n < 2; ++n) {
            float bv = b1[gcol0 + n * 16 + r16];
            #pragma unroll
            for (int m = 0; m < 4; ++m)
                #pragma unroll
                for (int r = 0; r < 4; ++r)
                    Cs[(m * 16 + rbase + r) * 36 + n * 16 + r16] =
                        f2bf(fast_gelu(acc[m][n][r] + bv));
        }
        #pragma unroll
        for (int pass = 0; pass < 4; ++pass) {
            int lr = pass * 16 + srow;
            int grow = bm * 128 + wr * 64 + lr;
            short8_t vv = *reinterpret_cast<const short8_t*>(&Cs[lr * 36 + scol]);
            *reinterpret_cast<short8_t*>(&H[(size_t)grow * 1024 + gcol0 + scol]) = vv;
        }
    }

    // phase boundary: all waves' H stores landed + Cs reads drained, block-wide
    asm volatile("s_waitcnt vmcnt(0) lgkmcnt(0)" ::: "memory");
    __builtin_amdgcn_sched_barrier(0);
    asm volatile("s_barrier" ::: "memory");

    // ================= Phase 2: fc2 + residual + LN -> out (f32) =================
    f32x4 acc2[4][4] = {};
    auto STAGE2 = [&](int buf, int kt) {       // 3 loads/thread; buffers at buf*24KB
        unsigned short* As = smem + buf * 12288;
        unsigned short* Bs = As + 4096;
        async16(&H[(arow0 + wv * 16 + srow_l) * 1024 + kt + sgran * 8],
                &As[(wv * 16) * 32]);
        #pragma unroll
        for (int i = 0; i < 2; ++i) {
            int row0 = wv * 32 + i * 16;
            async16(&W2[(size_t)(row0 + srow_l) * 1024 + kt + sgran * 8], &Bs[row0 * 32]);
        }
    };
    auto COMPUTE2 = [&](int buf) {
        unsigned short* As = smem + buf * 12288;
        unsigned short* Bs = As + 4096;
        short8_t af[4], bfr[4];
        #pragma unroll
        for (int m = 0; m < 4; ++m) {
            int row = wr * 64 + m * 16 + r16;
            af[m] = *reinterpret_cast<const short8_t*>(&As[row * 32 + gsw * 8]);
        }
        #pragma unroll
        for (int n = 0; n < 4; ++n) {
            int row = wc * 64 + n * 16 + r16;
            bfr[n] = *reinterpret_cast<const short8_t*>(&Bs[row * 32 + gsw * 8]);
        }
        #pragma unroll
        for (int m = 0; m < 4; ++m)
            #pragma unroll
            for (int n = 0; n < 4; ++n)
                acc2[m][n] = __builtin_amdgcn_mfma_f32_16x16x32_bf16(af[m], bfr[n], acc2[m][n], 0, 0, 0);
    };

    STAGE2(0, 0);
    STAGE2(1, 32);
    int cur = 0;
    for (int ks = 0; ks < 32; ++ks) {
        if (ks == 31) { asm volatile("s_waitcnt vmcnt(0)" ::: "memory"); }
        else          { asm volatile("s_waitcnt vmcnt(3)" ::: "memory"); }
        __builtin_amdgcn_sched_barrier(0);
        asm volatile("s_barrier" ::: "memory");
        COMPUTE2(cur);
        __builtin_amdgcn_sched_barrier(0);
        asm volatile("s_barrier" ::: "memory");
        if (ks + 2 < 32) STAGE2(cur, (ks + 2) << 5);
        cur ^= 1;
    }
    __builtin_amdgcn_sched_barrier(0);
    asm volatile("s_barrier" ::: "memory");

    float bv2[4];
    #pragma unroll
    for (int n = 0; n < 4; ++n) bv2[n] = b2[wc * 64 + n * 16 + r16];
    float* psum  = reinterpret_cast<float*>(smem + 19456);   // byte 38912: [128][4]
    float* psq   = psum + 512;
    float* stats = psq + 512;
    #pragma unroll
    for (int m = 0; m < 4; ++m) {
        #pragma unroll
        for (int r = 0; r < 4; ++r) {
            float s = 0.f, s2 = 0.f;
            #pragma unroll
            for (int n = 0; n < 4; ++n) {
                float v = acc2[m][n][r] + bv2[n];
                s += v; s2 += v * v;
            }
            s  += __shfl_xor(s, 1);  s  += __shfl_xor(s, 2);
            s  += __shfl_xor(s, 4);  s  += __shfl_xor(s, 8);
            s2 += __shfl_xor(s2, 1); s2 += __shfl_xor(s2, 2);
            s2 += __shfl_xor(s2, 4); s2 += __shfl_xor(s2, 8);
            if (r16 == 0) {
                int row = wr * 64 + m * 16 + g4 * 4 + r;
                psum[row * 4 + wc] = s;
                psq[row * 4 + wc]  = s2;
            }
        }
    }
    __syncthreads();
    if (tid < 128) {
        f32x4 a = *reinterpret_cast<const f32x4*>(&psum[tid * 4]);
        f32x4 b = *reinterpret_cast<const f32x4*>(&psq[tid * 4]);
        float mu  = (a[0] + a[1] + a[2] + a[3]) * 0.00390625f;
        float ex2 = (b[0] + b[1] + b[2] + b[3]) * 0.00390625f;
        stats[tid * 2]     = mu;
        stats[tid * 2 + 1] = rsqrtf(ex2 - mu * mu + 1e-5f);
    }
    __syncthreads();

    unsigned short* Cs = smem + wv * 2432;
    const int rbase = g4 * 4;
    const int srow = lane >> 3, scol = (lane & 7) * 8;
    const int gcol0 = wc * 64;
    f32x4 gm0 = *reinterpret_cast<const f32x4*>(&gamma[gcol0 + scol]);
    f32x4 gm1 = *reinterpret_cast<const f32x4*>(&gamma[gcol0 + scol + 4]);
    f32x4 bt0 = *reinterpret_cast<const f32x4*>(&beta[gcol0 + scol]);
    f32x4 bt1 = *reinterpret_cast<const f32x4*>(&beta[gcol0 + scol + 4]);
    #pragma unroll
    for (int p = 0; p < 2; ++p) {
        #pragma unroll
        for (int n = 0; n < 4; ++n)
            #pragma unroll
            for (int m2 = 0; m2 < 2; ++m2)
                #pragma unroll
                for (int r = 0; r < 4; ++r)
                    Cs[(m2 * 16 + rbase + r) * 76 + n * 16 + r16] =
                        f2bf(acc2[p * 2 + m2][n][r] + bv2[n]);
        #pragma unroll
        for (int rr = 0; rr < 4; ++rr) {
            int lr = rr * 8 + srow;
            int lrow = wr * 64 + p * 32 + lr;
            int grow = bm * 128 + lrow;
            float mu  = stats[lrow * 2];
            float inv = stats[lrow * 2 + 1];
            short8_t cv = *reinterpret_cast<const short8_t*>(&Cs[lr * 76 + scol]);
            short8_t rv = *reinterpret_cast<const short8_t*>(&A[(size_t)grow * 256 + gcol0 + scol]);
            float o[8];
            #pragma unroll
            for (int e = 0; e < 8; ++e) {
                float g = (e < 4) ? gm0[e] : gm1[e - 4];
                float bb = (e < 4) ? bt0[e] : bt1[e - 4];
                o[e] = bf2f((unsigned short)rv[e])
                     + (bf2f((unsigned short)cv[e]) - mu) * inv * g + bb;
            }
            float* outp = out + (size_t)grow * 256 + gcol0 + scol;
            f32x4 o0, o1;
            #pragma unroll
            for (int e = 0; e < 4; ++e) { o0[e] = o[e]; o1[e] = o[e + 4]; }
            *reinterpret_cast<f32x4*>(outp)     = o0;
            *reinterpret_cast<f32x4*>(outp + 4) = o1;
        }
    }
}

// ---------------- attention: one WAVE per (window, head), MFMA, setprio ----------------
__global__ __launch_bounds__(64) void attn_kernel(
    const unsigned short* __restrict__ qkv, const float* __restrict__ scales,
    const float* __restrict__ rpbf, unsigned short* __restrict__ out)
{
    constexpr int PO = 0;        // 64 x 72 ushorts
    constexpr int VO = 4608;     // 32 x 72 ushorts
    __shared__ unsigned short lds[6912];

    const int blk = blockIdx.x;
    const int h = blk & 7, wb = blk >> 3;
    const int lane = threadIdx.x;
    const int r16 = lane & 15, g4 = lane >> 4;

    const int wq = wb & 7, hb = (wb >> 3) & 7, dd = (wb >> 6) & 7, bb2 = wb >> 9;
    const int tok_base = ((bb2 * 8 + dd) * 56 + hb * 7) * 56 + wq * 7;
    const float sc = scales[h];

    {
        short8_t z = {};
        int d = lane >> 1, j0 = 48 + (lane & 1) * 8;
        *reinterpret_cast<short8_t*>(&lds[VO + d * 72 + j0]) = z;
    }
    for (int c = lane; c < 196; c += 64) {
        int j = c >> 2, gi = c & 3;
        int tok = tok_base + (j / 7) * 56 + (j % 7);
        short8_t raw = *reinterpret_cast<const short8_t*>(
            qkv + (size_t)tok * 768 + 512 + h * 32 + gi * 8);
        #pragma unroll
        for (int e = 0; e < 8; ++e)
            lds[VO + (gi * 8 + e) * 72 + j] = (unsigned short)raw[e];
    }

    short8_t qf[4], kf[4];
    #pragma unroll
    for (int sel = 0; sel < 2; ++sel) {
        #pragma unroll
        for (int mi = 0; mi < 4; ++mi) {
            int row = mi * 16 + r16;
            int tok = tok_base + (row / 7) * 56 + (row % 7);
            short8_t raw = *reinterpret_cast<const short8_t*>(
                qkv + (size_t)tok * 768 + sel * 256 + h * 32 + g4 * 8);
            float f[8]; float ss = 0.f;
            #pragma unroll
            for (int e = 0; e < 8; ++e) { f[e] = bf2f((unsigned short)raw[e]); ss += f[e] * f[e]; }
            ss += __shfl_xor(ss, 16); ss += __shfl_xor(ss, 32);
            float inv = 1.f / fmaxf(sqrtf(ss), 1e-12f);
            if (sel == 0) inv *= sc;
            short8_t o;
            #pragma unroll
            for (int e = 0; e < 8; ++e) o[e] = (short)f2bf(f[e] * inv);
            if (sel == 0) qf[mi] = o; else kf[mi] = o;
        }
    }
    __syncthreads();

    f32x4 acc[4][4] = {};
    __builtin_amdgcn_s_setprio(1);
    #pragma unroll
    for (int mi = 0; mi < 4; ++mi)
        #pragma unroll
        for (int ji = 0; ji < 4; ++ji)
            acc[mi][ji] = __builtin_amdgcn_mfma_f32_16x16x32_bf16(qf[mi], kf[ji], acc[mi][ji], 0, 0, 0);
    __builtin_amdgcn_s_setprio(0);

    const float* rbf = rpbf + h * 4096 + r16 * 16 + g4 * 4;
    f32x4 rbv[4][4];
    #pragma unroll
    for (int mi = 0; mi < 4; ++mi)
        #pragma unroll
        for (int ji = 0; ji < 4; ++ji)
            rbv[mi][ji] = *reinterpret_cast<const f32x4*>(&rbf[(mi * 4 + ji) * 256]);

    #pragma unroll
    for (int mi = 0; mi < 4; ++mi) {
        #pragma unroll
        for (int r = 0; r < 4; ++r) {
            int i = mi * 16 + g4 * 4 + r;
            float s[4]; float m = -1e30f;
            #pragma unroll
            for (int ji = 0; ji < 4; ++ji) {
                int j = ji * 16 + r16;
                float v = acc[mi][ji][r] + rbv[mi][ji][r];
                s[ji] = (j < 49) ? v : -1e30f;
                m = fmaxf(m, s[ji]);
            }
            m = fmaxf(m, __shfl_xor(m, 1)); m = fmaxf(m, __shfl_xor(m, 2));
            m = fmaxf(m, __shfl_xor(m, 4)); m = fmaxf(m, __shfl_xor(m, 8));
            float p[4]; float sum = 0.f;
            #pragma unroll
            for (int ji = 0; ji < 4; ++ji) {
                p[ji] = (s[ji] > -1e29f) ? __expf(s[ji] - m) : 0.f;
                sum += p[ji];
            }
            sum += __shfl_xor(sum, 1); sum += __shfl_xor(sum, 2);
            sum += __shfl_xor(sum, 4); sum += __shfl_xor(sum, 8);
            float rinv = 1.f / sum;
            #pragma unroll
            for (int ji = 0; ji < 4; ++ji) {
                int j = ji * 16 + r16;
                lds[PO + i * 72 + j] = f2bf(p[ji] * rinv);
            }
        }
    }
    __syncthreads();

    f32x4 acc2[4][2] = {};
    __builtin_amdgcn_s_setprio(1);
    #pragma unroll
    for (int ks = 0; ks < 2; ++ks) {
        short8_t pf[4], vf[2];
        int ko = ks * 32 + g4 * 8;
        #pragma unroll
        for (int mi = 0; mi < 4; ++mi)
            pf[mi] = *reinterpret_cast<const short8_t*>(&lds[PO + (mi * 16 + r16) * 72 + ko]);
        #pragma unroll
        for (int ni = 0; ni < 2; ++ni)
            vf[ni] = *reinterpret_cast<const short8_t*>(&lds[VO + (ni * 16 + r16) * 72 + ko]);
        #pragma unroll
        for (int mi = 0; mi < 4; ++mi)
            #pragma unroll
            for (int ni = 0; ni < 2; ++ni)
                acc2[mi][ni] = __builtin_amdgcn_mfma_f32_16x16x32_bf16(pf[mi], vf[ni], acc2[mi][ni], 0, 0, 0);
    }
    __builtin_amdgcn_s_setprio(0);

    #pragma unroll
    for (int mi = 0; mi < 4; ++mi)
        #pragma unroll
        for (int r = 0; r < 4; ++r) {
            int i = mi * 16 + g4 * 4 + r;
            if (i < 49) {
                size_t ob = (size_t)(wb * 49 + i) * 256 + h * 32;
                out[ob + r16]      = f2bf(acc2[mi][0][r]);
                out[ob + 16 + r16] = f2bf(acc2[mi][1][r]);
            }
        }
}

extern "C" void kernel_launch(void* const* d_in, const int* in_sizes, int n_in,
                              void* d_out, int out_size, void* d_ws, size_t ws_size,
                              hipStream_t stream) {
    const float* x      = (const float*)d_in[0];
    const float* qkv_w  = (const float*)d_in[1];
    const float* q_bias = (const float*)d_in[2];
    const float* v_bias = (const float*)d_in[3];
    const float* lscale = (const float*)d_in[4];
    const float* cpb_w1 = (const float*)d_in[5];
    const float* cpb_b1 = (const float*)d_in[6];
    const float* cpb_w2 = (const float*)d_in[7];
    const float* proj_w = (const float*)d_in[8];
    const float* proj_b = (const float*)d_in[9];
    const float* n1g    = (const float*)d_in[10];
    const float* n1b    = (const float*)d_in[11];
    const float* fc1_w  = (const float*)d_in[12];
    const float* fc1_b  = (const float*)d_in[13];
    const float* fc2_w  = (const float*)d_in[14];
    const float* fc2_b  = (const float*)d_in[15];
    const float* n2g    = (const float*)d_in[16];
    const float* n2b    = (const float*)d_in[17];
    const float* rct    = (const float*)d_in[18];
    const int*   rpi    = (const int*)d_in[19];

    char* ws = (char*)d_ws;
    unsigned short* qkv    = (unsigned short*)(ws);
    unsigned short* hbuf   = (unsigned short*)(ws);              // reuses qkv region
    unsigned short* attn_o = (unsigned short*)(ws + 154140672);
    unsigned short* xb     = (unsigned short*)(ws + 205520896);
    unsigned short* x1     = (unsigned short*)(ws + 205520896);
    unsigned short* wqkv   = (unsigned short*)(ws + 308281344);
    unsigned short* wproj  = (unsigned short*)(ws + 308674560);
    unsigned short* wfc1   = (unsigned short*)(ws + 308805632);
    unsigned short* wfc2   = (unsigned short*)(ws + 309329920);
    float*          rpbf   = (float*)(ws + 309854208);
    float*          scales = (float*)(ws + 310378496);
    float*          qkvb   = (float*)(ws + 310378528);
    float*          tableg = (float*)(ws + 310381600);

    const int M = 100352;

    conv_kernel<<<2048, 256, 0, stream>>>(x, xb, 25690112 / 4);
    conv4_kernel<<<768, 256, 0, stream>>>(qkv_w, wqkv, 49152,
                                          proj_w, wproj, 16384,
                                          fc1_w, wfc1, 65536,
                                          fc2_w, wfc2, 65536);
    prep_table_kernel<<<169, 256, 0, stream>>>(cpb_w1, cpb_b1, cpb_w2, rct, tableg);
    prep_expand_kernel<<<128, 256, 0, stream>>>(lscale, q_bias, v_bias, rpi, tableg,
                                                scales, rpbf, qkvb);
    // qkv = xb @ wqkv^T + qkv_bias
    gemm2_kernel<0><<<4704, 512, 0, stream>>>(xb, wqkv, qkvb, qkv, M, 768, 256, 6);
    // attention -> window-ordered (Bw*49, 256)
    attn_kernel<<<16384, 64, 0, stream>>>(qkv, scales, rpbf, attn_o);
    // x1 = xb + LN(attn_o @ wproj^T + proj_b)  [fused, scatter to natural order]
    gemm_ln_kernel<1, 0><<<784, 512, 0, stream>>>(attn_o, wproj, proj_b, xb, n1g, n1b,
                                                  x1, M, 256);
    // out = x1 + LN(gelu(x1@wfc1^T+b1) @ wfc2^T + b2)  [strip-fused MLP, h via L2]
    mlp2_kernel<<<784, 512, 0, stream>>>(x1, wfc1, fc1_b, hbuf, wfc2, fc2_b,
                                         n2g, n2b, (float*)d_out, M);
}

// Round 22
// 439.644 us; speedup vs baseline: 1.0181x; 1.0181x over previous
//
#include <hip/hip_runtime.h>
#include <hip/hip_bf16.h>

typedef __attribute__((ext_vector_type(8))) short short8_t;
typedef __attribute__((ext_vector_type(4))) float f32x4;

__device__ __forceinline__ float bf2f(unsigned short u) {
    return __uint_as_float(((unsigned)u) << 16);
}
__device__ __forceinline__ unsigned short f2bf(float f) {
    __hip_bfloat16 h = __float2bfloat16(f);
    return *reinterpret_cast<unsigned short*>(&h);
}

// exact-GELU via Abramowitz-Stegun 7.1.26 erf (|err| <= 1.5e-7), branch-free.
__device__ __forceinline__ float fast_gelu(float v) {
    float ax = fabsf(v) * 0.70710678118f;
    float t  = __builtin_amdgcn_rcpf(1.f + 0.3275911f * ax);
    float poly = t * (0.254829592f + t * (-0.284496736f + t * (1.421413741f
               + t * (-1.453152027f + t * 1.061405429f))));
    float e  = __expf(-ax * ax);
    float er = 1.f - poly * e;                 // erf(ax), ax >= 0
    float s  = (v >= 0.f) ? er : -er;
    return 0.5f * v * (1.f + s);
}

// async global->LDS, 16B per lane; LDS dest = wave-uniform base + lane*16
__device__ __forceinline__ void async16(const unsigned short* g, unsigned short* l) {
    __builtin_amdgcn_global_load_lds(
        (const __attribute__((address_space(1))) unsigned int*)g,
        (__attribute__((address_space(3))) unsigned int*)l,
        16, 0, 0);
}

// window-order row r (r = wb*49 + n) -> natural token index
__device__ __forceinline__ int win_row_to_token(int r) {
    int wb = r / 49, n = r - wb * 49;
    int wq = wb & 7, hb = (wb >> 3) & 7, d = (wb >> 6) & 7, b = wb >> 9;
    int hh = n / 7, ww2 = n - hh * 7;
    return ((b * 8 + d) * 56 + hb * 7 + hh) * 56 + wq * 7 + ww2;
}

// ---------------- f32 -> bf16 bulk convert ----------------
__global__ __launch_bounds__(256) void conv_kernel(
    const float* __restrict__ src, unsigned short* __restrict__ dst, int n4)
{
    int stride = gridDim.x * 256;
    for (int i = blockIdx.x * 256 + threadIdx.x; i < n4; i += stride) {
        float4 v = *reinterpret_cast<const float4*>(&src[(size_t)i * 4]);
        short4 o;
        o.x = (short)f2bf(v.x); o.y = (short)f2bf(v.y);
        o.z = (short)f2bf(v.z); o.w = (short)f2bf(v.w);
        *reinterpret_cast<short4*>(&dst[(size_t)i * 4]) = o;
    }
}

// 4 weight tensors in one dispatch (vec4 counts)
__global__ __launch_bounds__(256) void conv4_kernel(
    const float* __restrict__ s0, unsigned short* __restrict__ d0, int n0,
    const float* __restrict__ s1, unsigned short* __restrict__ d1, int n1,
    const float* __restrict__ s2, unsigned short* __restrict__ d2, int n2,
    const float* __restrict__ s3, unsigned short* __restrict__ d3, int n3)
{
    int stride = gridDim.x * 256;
    int total = n0 + n1 + n2 + n3;
    for (int i = blockIdx.x * 256 + threadIdx.x; i < total; i += stride) {
        const float* s; unsigned short* d; int j = i;
        if (j < n0) { s = s0; d = d0; }
        else if ((j -= n0) < n1) { s = s1; d = d1; }
        else if ((j -= n1) < n2) { s = s2; d = d2; }
        else { j -= n2; s = s3; d = d3; }
        float4 v = *reinterpret_cast<const float4*>(&s[(size_t)j * 4]);
        short4 o;
        o.x = (short)f2bf(v.x); o.y = (short)f2bf(v.y);
        o.z = (short)f2bf(v.z); o.w = (short)f2bf(v.w);
        *reinterpret_cast<short4*>(&d[(size_t)j * 4]) = o;
    }
}

// ---------------- prep stage 1: CPB-MLP table, one block per table row ----------------
__global__ __launch_bounds__(256) void prep_table_kernel(
    const float* __restrict__ w1, const float* __restrict__ b1,
    const float* __restrict__ w2, const float* __restrict__ tabin,
    float* __restrict__ tableg)
{
    const int i = blockIdx.x;          // 0..168
    const int t = threadIdx.x;
    const float c0 = tabin[i * 3], c1 = tabin[i * 3 + 1], c2 = tabin[i * 3 + 2];
    float part[8] = {0.f, 0.f, 0.f, 0.f, 0.f, 0.f, 0.f, 0.f};
    for (int j = t; j < 512; j += 256) {
        float hv = fmaxf(c0 * w1[j * 3] + c1 * w1[j * 3 + 1] + c2 * w1[j * 3 + 2] + b1[j], 0.f);
        #pragma unroll
        for (int h = 0; h < 8; ++h) part[h] += hv * w2[h * 512 + j];
    }
    #pragma unroll
    for (int h = 0; h < 8; ++h) {
        float v = part[h];
        v += __shfl_xor(v, 1);  v += __shfl_xor(v, 2);  v += __shfl_xor(v, 4);
        v += __shfl_xor(v, 8);  v += __shfl_xor(v, 16); v += __shfl_xor(v, 32);
        part[h] = v;
    }
    __shared__ float red[4][8];
    const int wv = t >> 6, lane = t & 63;
    if (lane == 0) {
        #pragma unroll
        for (int h = 0; h < 8; ++h) red[wv][h] = part[h];
    }
    __syncthreads();
    if (t < 8) tableg[i * 8 + t] = red[0][t] + red[1][t] + red[2][t] + red[3][t];
}

// ---------------- prep stage 2: scales, qkv bias, rpbf expansion ----------------
__global__ __launch_bounds__(256) void prep_expand_kernel(
    const float* __restrict__ logit_scale,
    const float* __restrict__ qb, const float* __restrict__ vb,
    const int* __restrict__ rpi, const float* __restrict__ tableg,
    float* __restrict__ scales, float* __restrict__ rpbf,
    float* __restrict__ qkvb)
{
    const int stride = gridDim.x * 256;
    const int gt = blockIdx.x * 256 + threadIdx.x;
    if (gt < 8) scales[gt] = expf(fminf(logit_scale[gt], 4.6051702f)); // ln(100)
    for (int i = gt; i < 768; i += stride) {
        float o;
        if (i < 256) o = qb[i];
        else if (i < 512) o = 0.f;
        else o = vb[i - 512];
        qkvb[i] = o;
    }
    for (int e = gt; e < 32768; e += stride) {
        int h = e >> 12, rem = e & 4095;
        int mi = rem >> 10, ji = (rem >> 8) & 3;
        int r16 = (rem >> 4) & 15, g4 = (rem >> 2) & 3, r = rem & 3;
        int i = mi * 16 + g4 * 4 + r, j = ji * 16 + r16;
        float val = 0.f;
        if (i < 49 && j < 49) {
            float xv = tableg[rpi[i * 49 + j] * 8 + h];
            val = 16.f / (1.f + expf(-xv));
        }
        rpbf[e] = val;
    }
}

// ---------------- GEMM: 128x128 tile, 8 waves x (64x32), 3-buffer pipeline ----------------
template<int ACT>
__global__ __launch_bounds__(512, 6) void gemm2_kernel(
    const unsigned short* __restrict__ A, const unsigned short* __restrict__ W,
    const float* __restrict__ bias, unsigned short* __restrict__ C,
    int M, int N, int K, int ntn)
{
    __shared__ unsigned short smem[24576];   // 48KB: 3 x (As 128x32 + Bs 128x32)
    const int tid = threadIdx.x;
    const int lane = tid & 63, wv = tid >> 6;
    const int wr = wv >> 2, wc = wv & 3;
    const int nwg = gridDim.x;
    const int virt = (blockIdx.x & 7) * (nwg >> 3) + (blockIdx.x >> 3);
    const int bn = virt % ntn, bm = virt / ntn;
    const size_t arow0 = (size_t)bm * 128;
    const size_t brow0 = (size_t)bn * 128;
    const int r16 = lane & 15, g4 = lane >> 4;
    const int srow_l = lane >> 2;
    const int sgran  = (lane & 3) ^ ((srow_l >> 1) & 3);
    f32x4 acc[4][2] = {};

    auto STAGE = [&](int buf, int kt) {      // 2 loads per thread
        unsigned short* As = smem + buf * 8192;
        unsigned short* Bs = As + 4096;
        int row0 = wv * 16;
        async16(&A[(arow0 + row0 + srow_l) * (size_t)K + kt + sgran * 8], &As[row0 * 32]);
        async16(&W[(brow0 + row0 + srow_l) * (size_t)K + kt + sgran * 8], &Bs[row0 * 32]);
    };
    auto COMPUTE = [&](int buf) {
        unsigned short* As = smem + buf * 8192;
        unsigned short* Bs = As + 4096;
        short8_t af[4], bfr[2];
        const int gsw = g4 ^ ((r16 >> 1) & 3);
        #pragma unroll
        for (int m = 0; m < 4; ++m) {
            int row = wr * 64 + m * 16 + r16;
            af[m] = *reinterpret_cast<const short8_t*>(&As[row * 32 + gsw * 8]);
        }
        #pragma unroll
        for (int n = 0; n < 2; ++n) {
            int row = wc * 32 + n * 16 + r16;
            bfr[n] = *reinterpret_cast<const short8_t*>(&Bs[row * 32 + gsw * 8]);
        }
        #pragma unroll
        for (int m = 0; m < 4; ++m)
            #pragma unroll
            for (int n = 0; n < 2; ++n)
                acc[m][n] = __builtin_amdgcn_mfma_f32_16x16x32_bf16(af[m], bfr[n], acc[m][n], 0, 0, 0);
    };

    const int nk = K >> 5;
    STAGE(0, 0);
    STAGE(1, 32);
    int cb = 0;
    for (int ks = 0; ks < nk; ++ks) {
        if (ks == nk - 1) { asm volatile("s_waitcnt vmcnt(0)" ::: "memory"); }
        else              { asm volatile("s_waitcnt vmcnt(2)" ::: "memory"); }
        __builtin_amdgcn_sched_barrier(0);
        asm volatile("s_barrier" ::: "memory");
        if (ks + 2 < nk) {
            int sb = cb + 2; if (sb >= 3) sb -= 3;
            STAGE(sb, (ks + 2) << 5);
        }
        __builtin_amdgcn_sched_barrier(0);
        COMPUTE(cb);
        cb = (cb == 2) ? 0 : cb + 1;
    }
    __builtin_amdgcn_sched_barrier(0);
    asm volatile("s_barrier" ::: "memory");  // LDS dead; epilogue overlays

    // ---- epilogue: per-wave 64x36 transpose -> coalesced stores ----
    unsigned short* Cs = smem + wv * 2304;   // 64 x 36 ushorts per wave
    const int rbase = g4 * 4;
    const int srow = lane >> 2, scol = (lane & 3) * 8;
    const int gcol0 = bn * 128 + wc * 32;
    #pragma unroll
    for (int n = 0; n < 2; ++n) {
        float bv = bias[gcol0 + n * 16 + r16];
        #pragma unroll
        for (int m = 0; m < 4; ++m)
            #pragma unroll
            for (int r = 0; r < 4; ++r) {
                float v = acc[m][n][r] + bv;
                if (ACT == 1) v = fast_gelu(v);
                Cs[(m * 16 + rbase + r) * 36 + n * 16 + r16] = f2bf(v);
            }
    }
    #pragma unroll
    for (int pass = 0; pass < 4; ++pass) {
        int lr = pass * 16 + srow;
        int grow = bm * 128 + wr * 64 + lr;
        short8_t vv = *reinterpret_cast<const short8_t*>(&Cs[lr * 36 + scol]);
        *reinterpret_cast<short8_t*>(&C[(size_t)grow * N + gcol0 + scol]) = vv;
    }
}

// ---------------- fused GEMM + residual + LayerNorm (N=256), 3-buffer pipeline ----------
template<int SCATTER, int OUT_F32>
__global__ __launch_bounds__(512) void gemm_ln_kernel(
    const unsigned short* __restrict__ A, const unsigned short* __restrict__ W,
    const float* __restrict__ bias, const unsigned short* __restrict__ resid,
    const float* __restrict__ gamma, const float* __restrict__ beta,
    void* __restrict__ Cv, int M, int K)
{
    __shared__ unsigned short smem[36864];   // 72KB, 3 buffers
    const int tid = threadIdx.x;
    const int lane = tid & 63, wv = tid >> 6;
    const int wr = wv >> 2, wc = wv & 3;
    const int nwg = gridDim.x;
    const int bm = (blockIdx.x & 7) * (nwg >> 3) + (blockIdx.x >> 3);
    const size_t arow0 = (size_t)bm * 128;
    const int r16 = lane & 15, g4 = lane >> 4;
    const int srow_l = lane >> 2;
    const int sgran = (lane & 3) ^ ((srow_l >> 1) & 3);
    f32x4 acc[4][4] = {};

    auto STAGE = [&](int buf, int kt) {
        unsigned short* As = smem + buf * 12288;
        unsigned short* Bs = As + 4096;
        async16(&A[(arow0 + wv * 16 + srow_l) * (size_t)K + kt + sgran * 8],
                &As[(wv * 16) * 32]);
        #pragma unroll
        for (int i = 0; i < 2; ++i) {
            int row0 = wv * 32 + i * 16;
            async16(&W[(size_t)(row0 + srow_l) * K + kt + sgran * 8], &Bs[row0 * 32]);
        }
    };
    auto COMPUTE = [&](int buf) {
        unsigned short* As = smem + buf * 12288;
        unsigned short* Bs = As + 4096;
        short8_t af[4], bfr[4];
        const int gsw = g4 ^ ((r16 >> 1) & 3);
        #pragma unroll
        for (int m = 0; m < 4; ++m) {
            int row = wr * 64 + m * 16 + r16;
            af[m] = *reinterpret_cast<const short8_t*>(&As[row * 32 + gsw * 8]);
        }
        #pragma unroll
        for (int n = 0; n < 4; ++n) {
            int row = wc * 64 + n * 16 + r16;
            bfr[n] = *reinterpret_cast<const short8_t*>(&Bs[row * 32 + gsw * 8]);
        }
        #pragma unroll
        for (int m = 0; m < 4; ++m)
            #pragma unroll
            for (int n = 0; n < 4; ++n)
                acc[m][n] = __builtin_amdgcn_mfma_f32_16x16x32_bf16(af[m], bfr[n], acc[m][n], 0, 0, 0);
    };

    const int nk = K >> 5;
    STAGE(0, 0);
    STAGE(1, 32);
    int cb = 0;
    for (int ks = 0; ks < nk; ++ks) {
        if (ks == nk - 1) { asm volatile("s_waitcnt vmcnt(0)" ::: "memory"); }
        else              { asm volatile("s_waitcnt vmcnt(3)" ::: "memory"); }
        __builtin_amdgcn_sched_barrier(0);
        asm volatile("s_barrier" ::: "memory");
        if (ks + 2 < nk) {
            int sb = cb + 2; if (sb >= 3) sb -= 3;
            STAGE(sb, (ks + 2) << 5);
        }
        __builtin_amdgcn_sched_barrier(0);
        COMPUTE(cb);
        cb = (cb == 2) ? 0 : cb + 1;
    }
    __builtin_amdgcn_sched_barrier(0);
    asm volatile("s_barrier" ::: "memory");

    float bv[4];
    #pragma unroll
    for (int n = 0; n < 4; ++n) bv[n] = bias[wc * 64 + n * 16 + r16];
    float* psum  = reinterpret_cast<float*>(smem + 19456);   // [128][4]
    float* psq   = psum + 512;                               // [128][4]
    float* stats = psq + 512;                                // [128][2]
    #pragma unroll
    for (int m = 0; m < 4; ++m) {
        #pragma unroll
        for (int r = 0; r < 4; ++r) {
            float s = 0.f, s2 = 0.f;
            #pragma unroll
            for (int n = 0; n < 4; ++n) {
                float v = acc[m][n][r] + bv[n];
                s += v; s2 += v * v;
            }
            s  += __shfl_xor(s, 1);  s  += __shfl_xor(s, 2);
            s  += __shfl_xor(s, 4);  s  += __shfl_xor(s, 8);
            s2 += __shfl_xor(s2, 1); s2 += __shfl_xor(s2, 2);
            s2 += __shfl_xor(s2, 4); s2 += __shfl_xor(s2, 8);
            if (r16 == 0) {
                int row = wr * 64 + m * 16 + g4 * 4 + r;
                psum[row * 4 + wc] = s;
                psq[row * 4 + wc]  = s2;
            }
        }
    }
    __syncthreads();
    if (tid < 128) {
        f32x4 a = *reinterpret_cast<const f32x4*>(&psum[tid * 4]);
        f32x4 b = *reinterpret_cast<const f32x4*>(&psq[tid * 4]);
        float mu  = (a[0] + a[1] + a[2] + a[3]) * 0.00390625f;
        float ex2 = (b[0] + b[1] + b[2] + b[3]) * 0.00390625f;
        stats[tid * 2]     = mu;
        stats[tid * 2 + 1] = rsqrtf(ex2 - mu * mu + 1e-5f);
    }
    __syncthreads();

    unsigned short* Cs = smem + wv * 2432;
    const int rbase = g4 * 4;
    const int srow = lane >> 3, scol = (lane & 7) * 8;
    const int gcol0 = wc * 64;
    f32x4 gm0 = *reinterpret_cast<const f32x4*>(&gamma[gcol0 + scol]);
    f32x4 gm1 = *reinterpret_cast<const f32x4*>(&gamma[gcol0 + scol + 4]);
    f32x4 bt0 = *reinterpret_cast<const f32x4*>(&beta[gcol0 + scol]);
    f32x4 bt1 = *reinterpret_cast<const f32x4*>(&beta[gcol0 + scol + 4]);
    #pragma unroll
    for (int p = 0; p < 2; ++p) {
        #pragma unroll
        for (int n = 0; n < 4; ++n)
            #pragma unroll
            for (int m2 = 0; m2 < 2; ++m2)
                #pragma unroll
                for (int r = 0; r < 4; ++r)
                    Cs[(m2 * 16 + rbase + r) * 76 + n * 16 + r16] =
                        f2bf(acc[p * 2 + m2][n][r] + bv[n]);
        #pragma unroll
        for (int rr = 0; rr < 4; ++rr) {
            int lr = rr * 8 + srow;
            int lrow = wr * 64 + p * 32 + lr;
            int grow = bm * 128 + lrow;
            size_t orow = SCATTER ? (size_t)win_row_to_token(grow) : (size_t)grow;
            float mu  = stats[lrow * 2];
            float inv = stats[lrow * 2 + 1];
            short8_t cv = *reinterpret_cast<const short8_t*>(&Cs[lr * 76 + scol]);
            short8_t rv = *reinterpret_cast<const short8_t*>(&resid[orow * 256 + gcol0 + scol]);
            float o[8];
            #pragma unroll
            for (int e = 0; e < 8; ++e) {
                float g = (e < 4) ? gm0[e] : gm1[e - 4];
                float bb = (e < 4) ? bt0[e] : bt1[e - 4];
                o[e] = bf2f((unsigned short)rv[e])
                     + (bf2f((unsigned short)cv[e]) - mu) * inv * g + bb;
            }
            if (OUT_F32) {
                float* outp = (float*)Cv + orow * 256 + gcol0 + scol;
                f32x4 o0, o1;
                #pragma unroll
                for (int e = 0; e < 4; ++e) { o0[e] = o[e]; o1[e] = o[e + 4]; }
                *reinterpret_cast<f32x4*>(outp)     = o0;
                *reinterpret_cast<f32x4*>(outp + 4) = o1;
            } else {
                unsigned short* outp = (unsigned short*)Cv + orow * 256 + gcol0 + scol;
                short8_t ov;
                #pragma unroll
                for (int e = 0; e < 8; ++e) ov[e] = (short)f2bf(o[e]);
                *reinterpret_cast<short8_t*>(outp) = ov;
            }
        }
    }
}

// ---------------- attention: one WAVE per (window, head), MFMA, setprio on MFMA ----------
__global__ __launch_bounds__(64) void attn_kernel(
    const unsigned short* __restrict__ qkv, const float* __restrict__ scales,
    const float* __restrict__ rpbf, unsigned short* __restrict__ out)
{
    constexpr int PO = 0;        // 64 x 72 ushorts
    constexpr int VO = 4608;     // 32 x 72 ushorts
    __shared__ unsigned short lds[6912];

    const int blk = blockIdx.x;
    const int h = blk & 7, wb = blk >> 3;
    const int lane = threadIdx.x;
    const int r16 = lane & 15, g4 = lane >> 4;

    const int wq = wb & 7, hb = (wb >> 3) & 7, dd = (wb >> 6) & 7, bb2 = wb >> 9;
    const int tok_base = ((bb2 * 8 + dd) * 56 + hb * 7) * 56 + wq * 7;
    const float sc = scales[h];

    // zero V^T j-pad (j 48..63)
    {
        short8_t z = {};
        int d = lane >> 1, j0 = 48 + (lane & 1) * 8;
        *reinterpret_cast<short8_t*>(&lds[VO + d * 72 + j0]) = z;
    }
    // stage V^T via register transpose: short8 row loads -> 8 scalar LDS writes
    for (int c = lane; c < 196; c += 64) {
        int j = c >> 2, gi = c & 3;
        int tok = tok_base + (j / 7) * 56 + (j % 7);
        short8_t raw = *reinterpret_cast<const short8_t*>(
            qkv + (size_t)tok * 768 + 512 + h * 32 + gi * 8);
        #pragma unroll
        for (int e = 0; e < 8; ++e)
            lds[VO + (gi * 8 + e) * 72 + j] = (unsigned short)raw[e];
    }

    // Q/K fragments: direct global load + cross-lane l2norm
    short8_t qf[4], kf[4];
    #pragma unroll
    for (int sel = 0; sel < 2; ++sel) {
        #pragma unroll
        for (int mi = 0; mi < 4; ++mi) {
            int row = mi * 16 + r16;
            int tok = tok_base + (row / 7) * 56 + (row % 7);
            short8_t raw = *reinterpret_cast<const short8_t*>(
                qkv + (size_t)tok * 768 + sel * 256 + h * 32 + g4 * 8);
            float f[8]; float ss = 0.f;
            #pragma unroll
            for (int e = 0; e < 8; ++e) { f[e] = bf2f((unsigned short)raw[e]); ss += f[e] * f[e]; }
            ss += __shfl_xor(ss, 16); ss += __shfl_xor(ss, 32);
            float inv = 1.f / fmaxf(sqrtf(ss), 1e-12f);
            if (sel == 0) inv *= sc;
            short8_t o;
            #pragma unroll
            for (int e = 0; e < 8; ++e) o[e] = (short)f2bf(f[e] * inv);
            if (sel == 0) qf[mi] = o; else kf[mi] = o;
        }
    }
    __syncthreads();   // V^T staged

    // ---- QK^T: 4x4 tiles, setprio(1) cluster ----
    f32x4 acc[4][4] = {};
    __builtin_amdgcn_s_setprio(1);
    #pragma unroll
    for (int mi = 0; mi < 4; ++mi)
        #pragma unroll
        for (int ji = 0; ji < 4; ++ji)
            acc[mi][ji] = __builtin_amdgcn_mfma_f32_16x16x32_bf16(qf[mi], kf[ji], acc[mi][ji], 0, 0, 0);
    __builtin_amdgcn_s_setprio(0);

    // ---- prefetch rpb fragments (fragment-layout table, pads = 0) ----
    const float* rbf = rpbf + h * 4096 + r16 * 16 + g4 * 4;
    f32x4 rbv[4][4];
    #pragma unroll
    for (int mi = 0; mi < 4; ++mi)
        #pragma unroll
        for (int ji = 0; ji < 4; ++ji)
            rbv[mi][ji] = *reinterpret_cast<const f32x4*>(&rbf[(mi * 4 + ji) * 256]);

    // ---- softmax over j, P -> LDS bf16 ----
    #pragma unroll
    for (int mi = 0; mi < 4; ++mi) {
        #pragma unroll
        for (int r = 0; r < 4; ++r) {
            int i = mi * 16 + g4 * 4 + r;
            float s[4]; float m = -1e30f;
            #pragma unroll
            for (int ji = 0; ji < 4; ++ji) {
                int j = ji * 16 + r16;
                float v = acc[mi][ji][r] + rbv[mi][ji][r];
                s[ji] = (j < 49) ? v : -1e30f;
                m = fmaxf(m, s[ji]);
            }
            m = fmaxf(m, __shfl_xor(m, 1)); m = fmaxf(m, __shfl_xor(m, 2));
            m = fmaxf(m, __shfl_xor(m, 4)); m = fmaxf(m, __shfl_xor(m, 8));
            float p[4]; float sum = 0.f;
            #pragma unroll
            for (int ji = 0; ji < 4; ++ji) {
                p[ji] = (s[ji] > -1e29f) ? __expf(s[ji] - m) : 0.f;
                sum += p[ji];
            }
            sum += __shfl_xor(sum, 1); sum += __shfl_xor(sum, 2);
            sum += __shfl_xor(sum, 4); sum += __shfl_xor(sum, 8);
            float rinv = 1.f / sum;
            #pragma unroll
            for (int ji = 0; ji < 4; ++ji) {
                int j = ji * 16 + r16;
                lds[PO + i * 72 + j] = f2bf(p[ji] * rinv);
            }
        }
    }
    __syncthreads();   // P writes drained before ds_read

    // ---- PV: setprio(1) cluster ----
    f32x4 acc2[4][2] = {};
    __builtin_amdgcn_s_setprio(1);
    #pragma unroll
    for (int ks = 0; ks < 2; ++ks) {
        short8_t pf[4], vf[2];
        int ko = ks * 32 + g4 * 8;
        #pragma unroll
        for (int mi = 0; mi < 4; ++mi)
            pf[mi] = *reinterpret_cast<const short8_t*>(&lds[PO + (mi * 16 + r16) * 72 + ko]);
        #pragma unroll
        for (int ni = 0; ni < 2; ++ni)
            vf[ni] = *reinterpret_cast<const short8_t*>(&lds[VO + (ni * 16 + r16) * 72 + ko]);
        #pragma unroll
        for (int mi = 0; mi < 4; ++mi)
            #pragma unroll
            for (int ni = 0; ni < 2; ++ni)
                acc2[mi][ni] = __builtin_amdgcn_mfma_f32_16x16x32_bf16(pf[mi], vf[ni], acc2[mi][ni], 0, 0, 0);
    }
    __builtin_amdgcn_s_setprio(0);

    #pragma unroll
    for (int mi = 0; mi < 4; ++mi)
        #pragma unroll
        for (int r = 0; r < 4; ++r) {
            int i = mi * 16 + g4 * 4 + r;
            if (i < 49) {
                size_t ob = (size_t)(wb * 49 + i) * 256 + h * 32;
                out[ob + r16]      = f2bf(acc2[mi][0][r]);
                out[ob + 16 + r16] = f2bf(acc2[mi][1][r]);
            }
        }
}

extern "C" void kernel_launch(void* const* d_in, const int* in_sizes, int n_in,
                              void* d_out, int out_size, void* d_ws, size_t ws_size,
                              hipStream_t stream) {
    const float* x      = (const float*)d_in[0];
    const float* qkv_w  = (const float*)d_in[1];
    const float* q_bias = (const float*)d_in[2];
    const float* v_bias = (const float*)d_in[3];
    const float* lscale = (const float*)d_in[4];
    const float* cpb_w1 = (const float*)d_in[5];
    const float* cpb_b1 = (const float*)d_in[6];
    const float* cpb_w2 = (const float*)d_in[7];
    const float* proj_w = (const float*)d_in[8];
    const float* proj_b = (const float*)d_in[9];
    const float* n1g    = (const float*)d_in[10];
    const float* n1b    = (const float*)d_in[11];
    const float* fc1_w  = (const float*)d_in[12];
    const float* fc1_b  = (const float*)d_in[13];
    const float* fc2_w  = (const float*)d_in[14];
    const float* fc2_b  = (const float*)d_in[15];
    const float* n2g    = (const float*)d_in[16];
    const float* n2b    = (const float*)d_in[17];
    const float* rct    = (const float*)d_in[18];
    const int*   rpi    = (const int*)d_in[19];

    char* ws = (char*)d_ws;
    unsigned short* qkv    = (unsigned short*)(ws);
    unsigned short* hbuf   = (unsigned short*)(ws);
    unsigned short* attn_o = (unsigned short*)(ws + 154140672);
    unsigned short* xb     = (unsigned short*)(ws + 205520896);
    unsigned short* x1     = (unsigned short*)(ws + 205520896);
    unsigned short* wqkv   = (unsigned short*)(ws + 308281344);
    unsigned short* wproj  = (unsigned short*)(ws + 308674560);
    unsigned short* wfc1   = (unsigned short*)(ws + 308805632);
    unsigned short* wfc2   = (unsigned short*)(ws + 309329920);
    float*          rpbf   = (float*)(ws + 309854208);
    float*          scales = (float*)(ws + 310378496);
    float*          qkvb   = (float*)(ws + 310378528);
    float*          tableg = (float*)(ws + 310381600);

    const int M = 100352;

    conv_kernel<<<2048, 256, 0, stream>>>(x, xb, 25690112 / 4);
    conv4_kernel<<<768, 256, 0, stream>>>(qkv_w, wqkv, 49152,
                                          proj_w, wproj, 16384,
                                          fc1_w, wfc1, 65536,
                                          fc2_w, wfc2, 65536);
    prep_table_kernel<<<169, 256, 0, stream>>>(cpb_w1, cpb_b1, cpb_w2, rct, tableg);
    prep_expand_kernel<<<128, 256, 0, stream>>>(lscale, q_bias, v_bias, rpi, tableg,
                                                scales, rpbf, qkvb);
    // qkv = xb @ wqkv^T + qkv_bias   (128x128 tiles: 784 x 6)
    gemm2_kernel<0><<<4704, 512, 0, stream>>>(xb, wqkv, qkvb, qkv, M, 768, 256, 6);
    // attention -> window-ordered (Bw*49, 256)
    attn_kernel<<<16384, 64, 0, stream>>>(qkv, scales, rpbf, attn_o);
    // x1 = xb + LN(attn_o @ wproj^T + proj_b)  [fused, scatter to natural order]
    gemm_ln_kernel<1, 0><<<784, 512, 0, stream>>>(attn_o, wproj, proj_b, xb, n1g, n1b,
                                                  x1, M, 256);
    // h = gelu(x1 @ wfc1^T + fc1_b)   (128x128 tiles: 784 x 8)
    gemm2_kernel<1><<<6272, 512, 0, stream>>>(x1, wfc1, fc1_b, hbuf, M, 1024, 256, 8);
    // out = x1 + LN(h @ wfc2^T + fc2_b)  [fused, f32 output]
    gemm_ln_kernel<0, 1><<<784, 512, 0, stream>>>(hbuf, wfc2, fc2_b, x1, n2g, n2b,
                                                  d_out, M, 1024);
}

// Round 23
// 426.420 us; speedup vs baseline: 1.0496x; 1.0310x over previous
//
#include <hip/hip_runtime.h>
#include <hip/hip_bf16.h>

typedef __attribute__((ext_vector_type(8))) short short8_t;
typedef __attribute__((ext_vector_type(4))) float f32x4;

__device__ __forceinline__ float bf2f(unsigned short u) {
    return __uint_as_float(((unsigned)u) << 16);
}
__device__ __forceinline__ unsigned short f2bf(float f) {
    __hip_bfloat16 h = __float2bfloat16(f);
    return *reinterpret_cast<unsigned short*>(&h);
}

// exact-GELU via Abramowitz-Stegun 7.1.26 erf (|err| <= 1.5e-7), branch-free.
__device__ __forceinline__ float fast_gelu(float v) {
    float ax = fabsf(v) * 0.70710678118f;
    float t  = __builtin_amdgcn_rcpf(1.f + 0.3275911f * ax);
    float poly = t * (0.254829592f + t * (-0.284496736f + t * (1.421413741f
               + t * (-1.453152027f + t * 1.061405429f))));
    float e  = __expf(-ax * ax);
    float er = 1.f - poly * e;                 // erf(ax), ax >= 0
    float s  = (v >= 0.f) ? er : -er;
    return 0.5f * v * (1.f + s);
}

// async global->LDS, 16B per lane; LDS dest = wave-uniform base + lane*16
__device__ __forceinline__ void async16(const unsigned short* g, unsigned short* l) {
    __builtin_amdgcn_global_load_lds(
        (const __attribute__((address_space(1))) unsigned int*)g,
        (__attribute__((address_space(3))) unsigned int*)l,
        16, 0, 0);
}

// window-order row r (r = wb*49 + n) -> natural token index
__device__ __forceinline__ int win_row_to_token(int r) {
    int wb = r / 49, n = r - wb * 49;
    int wq = wb & 7, hb = (wb >> 3) & 7, d = (wb >> 6) & 7, b = wb >> 9;
    int hh = n / 7, ww2 = n - hh * 7;
    return ((b * 8 + d) * 56 + hb * 7 + hh) * 56 + wq * 7 + ww2;
}

// ---------------- f32 -> bf16 bulk convert ----------------
__global__ __launch_bounds__(256) void conv_kernel(
    const float* __restrict__ src, unsigned short* __restrict__ dst, int n4)
{
    int stride = gridDim.x * 256;
    for (int i = blockIdx.x * 256 + threadIdx.x; i < n4; i += stride) {
        float4 v = *reinterpret_cast<const float4*>(&src[(size_t)i * 4]);
        short4 o;
        o.x = (short)f2bf(v.x); o.y = (short)f2bf(v.y);
        o.z = (short)f2bf(v.z); o.w = (short)f2bf(v.w);
        *reinterpret_cast<short4*>(&dst[(size_t)i * 4]) = o;
    }
}

// 4 weight tensors in one dispatch (vec4 counts)
__global__ __launch_bounds__(256) void conv4_kernel(
    const float* __restrict__ s0, unsigned short* __restrict__ d0, int n0,
    const float* __restrict__ s1, unsigned short* __restrict__ d1, int n1,
    const float* __restrict__ s2, unsigned short* __restrict__ d2, int n2,
    const float* __restrict__ s3, unsigned short* __restrict__ d3, int n3)
{
    int stride = gridDim.x * 256;
    int total = n0 + n1 + n2 + n3;
    for (int i = blockIdx.x * 256 + threadIdx.x; i < total; i += stride) {
        const float* s; unsigned short* d; int j = i;
        if (j < n0) { s = s0; d = d0; }
        else if ((j -= n0) < n1) { s = s1; d = d1; }
        else if ((j -= n1) < n2) { s = s2; d = d2; }
        else { j -= n2; s = s3; d = d3; }
        float4 v = *reinterpret_cast<const float4*>(&s[(size_t)j * 4]);
        short4 o;
        o.x = (short)f2bf(v.x); o.y = (short)f2bf(v.y);
        o.z = (short)f2bf(v.z); o.w = (short)f2bf(v.w);
        *reinterpret_cast<short4*>(&d[(size_t)j * 4]) = o;
    }
}

// ---------------- prep stage 1: CPB-MLP table, one block per table row ----------------
__global__ __launch_bounds__(256) void prep_table_kernel(
    const float* __restrict__ w1, const float* __restrict__ b1,
    const float* __restrict__ w2, const float* __restrict__ tabin,
    float* __restrict__ tableg)
{
    const int i = blockIdx.x;          // 0..168
    const int t = threadIdx.x;
    const float c0 = tabin[i * 3], c1 = tabin[i * 3 + 1], c2 = tabin[i * 3 + 2];
    float part[8] = {0.f, 0.f, 0.f, 0.f, 0.f, 0.f, 0.f, 0.f};
    for (int j = t; j < 512; j += 256) {
        float hv = fmaxf(c0 * w1[j * 3] + c1 * w1[j * 3 + 1] + c2 * w1[j * 3 + 2] + b1[j], 0.f);
        #pragma unroll
        for (int h = 0; h < 8; ++h) part[h] += hv * w2[h * 512 + j];
    }
    #pragma unroll
    for (int h = 0; h < 8; ++h) {
        float v = part[h];
        v += __shfl_xor(v, 1);  v += __shfl_xor(v, 2);  v += __shfl_xor(v, 4);
        v += __shfl_xor(v, 8);  v += __shfl_xor(v, 16); v += __shfl_xor(v, 32);
        part[h] = v;
    }
    __shared__ float red[4][8];
    const int wv = t >> 6, lane = t & 63;
    if (lane == 0) {
        #pragma unroll
        for (int h = 0; h < 8; ++h) red[wv][h] = part[h];
    }
    __syncthreads();
    if (t < 8) tableg[i * 8 + t] = red[0][t] + red[1][t] + red[2][t] + red[3][t];
}

// ---------------- prep stage 2: scales, qkv bias, rpbf expansion ----------------
// rpbf layout [h][mi][ji][r16][g4][r] = rpb[i][j] with i = mi*16 + r16,
// j = ji*16 + g4*4 + r  (matches swapped-QK S^T fragment orientation).
__global__ __launch_bounds__(256) void prep_expand_kernel(
    const float* __restrict__ logit_scale,
    const float* __restrict__ qb, const float* __restrict__ vb,
    const int* __restrict__ rpi, const float* __restrict__ tableg,
    float* __restrict__ scales, float* __restrict__ rpbf,
    float* __restrict__ qkvb)
{
    const int stride = gridDim.x * 256;
    const int gt = blockIdx.x * 256 + threadIdx.x;
    if (gt < 8) scales[gt] = expf(fminf(logit_scale[gt], 4.6051702f)); // ln(100)
    for (int i = gt; i < 768; i += stride) {
        float o;
        if (i < 256) o = qb[i];
        else if (i < 512) o = 0.f;
        else o = vb[i - 512];
        qkvb[i] = o;
    }
    for (int e = gt; e < 32768; e += stride) {
        int h = e >> 12, rem = e & 4095;
        int mi = rem >> 10, ji = (rem >> 8) & 3;
        int r16 = (rem >> 4) & 15, g4 = (rem >> 2) & 3, r = rem & 3;
        int i = mi * 16 + r16, j = ji * 16 + g4 * 4 + r;   // swapped orientation
        float val = 0.f;
        if (i < 49 && j < 49) {
            float xv = tableg[rpi[i * 49 + j] * 8 + h];
            val = 16.f / (1.f + expf(-xv));
        }
        rpbf[e] = val;
    }
}

// ---------------- GEMM: 128x128 tile, 8 waves x (64x32), 3-buffer pipeline ----------------
template<int ACT>
__global__ __launch_bounds__(512, 6) void gemm2_kernel(
    const unsigned short* __restrict__ A, const unsigned short* __restrict__ W,
    const float* __restrict__ bias, unsigned short* __restrict__ C,
    int M, int N, int K, int ntn)
{
    __shared__ unsigned short smem[24576];   // 48KB: 3 x (As 128x32 + Bs 128x32)
    const int tid = threadIdx.x;
    const int lane = tid & 63, wv = tid >> 6;
    const int wr = wv >> 2, wc = wv & 3;
    const int nwg = gridDim.x;
    const int virt = (blockIdx.x & 7) * (nwg >> 3) + (blockIdx.x >> 3);
    const int bn = virt % ntn, bm = virt / ntn;
    const size_t arow0 = (size_t)bm * 128;
    const size_t brow0 = (size_t)bn * 128;
    const int r16 = lane & 15, g4 = lane >> 4;
    const int srow_l = lane >> 2;
    const int sgran  = (lane & 3) ^ ((srow_l >> 1) & 3);
    f32x4 acc[4][2] = {};

    auto STAGE = [&](int buf, int kt) {      // 2 loads per thread
        unsigned short* As = smem + buf * 8192;
        unsigned short* Bs = As + 4096;
        int row0 = wv * 16;
        async16(&A[(arow0 + row0 + srow_l) * (size_t)K + kt + sgran * 8], &As[row0 * 32]);
        async16(&W[(brow0 + row0 + srow_l) * (size_t)K + kt + sgran * 8], &Bs[row0 * 32]);
    };
    auto COMPUTE = [&](int buf) {
        unsigned short* As = smem + buf * 8192;
        unsigned short* Bs = As + 4096;
        short8_t af[4], bfr[2];
        const int gsw = g4 ^ ((r16 >> 1) & 3);
        #pragma unroll
        for (int m = 0; m < 4; ++m) {
            int row = wr * 64 + m * 16 + r16;
            af[m] = *reinterpret_cast<const short8_t*>(&As[row * 32 + gsw * 8]);
        }
        #pragma unroll
        for (int n = 0; n < 2; ++n) {
            int row = wc * 32 + n * 16 + r16;
            bfr[n] = *reinterpret_cast<const short8_t*>(&Bs[row * 32 + gsw * 8]);
        }
        #pragma unroll
        for (int m = 0; m < 4; ++m)
            #pragma unroll
            for (int n = 0; n < 2; ++n)
                acc[m][n] = __builtin_amdgcn_mfma_f32_16x16x32_bf16(af[m], bfr[n], acc[m][n], 0, 0, 0);
    };

    const int nk = K >> 5;
    STAGE(0, 0);
    STAGE(1, 32);
    int cb = 0;
    for (int ks = 0; ks < nk; ++ks) {
        if (ks == nk - 1) { asm volatile("s_waitcnt vmcnt(0)" ::: "memory"); }
        else              { asm volatile("s_waitcnt vmcnt(2)" ::: "memory"); }
        __builtin_amdgcn_sched_barrier(0);
        asm volatile("s_barrier" ::: "memory");
        if (ks + 2 < nk) {
            int sb = cb + 2; if (sb >= 3) sb -= 3;
            STAGE(sb, (ks + 2) << 5);
        }
        __builtin_amdgcn_sched_barrier(0);
        COMPUTE(cb);
        cb = (cb == 2) ? 0 : cb + 1;
    }
    __builtin_amdgcn_sched_barrier(0);
    asm volatile("s_barrier" ::: "memory");  // LDS dead; epilogue overlays

    // ---- epilogue: per-wave 64x36 transpose -> coalesced stores ----
    unsigned short* Cs = smem + wv * 2304;   // 64 x 36 ushorts per wave
    const int rbase = g4 * 4;
    const int srow = lane >> 2, scol = (lane & 3) * 8;
    const int gcol0 = bn * 128 + wc * 32;
    #pragma unroll
    for (int n = 0; n < 2; ++n) {
        float bv = bias[gcol0 + n * 16 + r16];
        #pragma unroll
        for (int m = 0; m < 4; ++m)
            #pragma unroll
            for (int r = 0; r < 4; ++r) {
                float v = acc[m][n][r] + bv;
                if (ACT == 1) v = fast_gelu(v);
                Cs[(m * 16 + rbase + r) * 36 + n * 16 + r16] = f2bf(v);
            }
    }
    #pragma unroll
    for (int pass = 0; pass < 4; ++pass) {
        int lr = pass * 16 + srow;
        int grow = bm * 128 + wr * 64 + lr;
        short8_t vv = *reinterpret_cast<const short8_t*>(&Cs[lr * 36 + scol]);
        *reinterpret_cast<short8_t*>(&C[(size_t)grow * N + gcol0 + scol]) = vv;
    }
}

// ---------------- fused GEMM + residual + LayerNorm (N=256), 3-buffer pipeline ----------
template<int SCATTER, int OUT_F32>
__global__ __launch_bounds__(512) void gemm_ln_kernel(
    const unsigned short* __restrict__ A, const unsigned short* __restrict__ W,
    const float* __restrict__ bias, const unsigned short* __restrict__ resid,
    const float* __restrict__ gamma, const float* __restrict__ beta,
    void* __restrict__ Cv, int M, int K)
{
    __shared__ unsigned short smem[36864];   // 72KB, 3 buffers
    const int tid = threadIdx.x;
    const int lane = tid & 63, wv = tid >> 6;
    const int wr = wv >> 2, wc = wv & 3;
    const int nwg = gridDim.x;
    const int bm = (blockIdx.x & 7) * (nwg >> 3) + (blockIdx.x >> 3);
    const size_t arow0 = (size_t)bm * 128;
    const int r16 = lane & 15, g4 = lane >> 4;
    const int srow_l = lane >> 2;
    const int sgran = (lane & 3) ^ ((srow_l >> 1) & 3);
    f32x4 acc[4][4] = {};

    auto STAGE = [&](int buf, int kt) {
        unsigned short* As = smem + buf * 12288;
        unsigned short* Bs = As + 4096;
        async16(&A[(arow0 + wv * 16 + srow_l) * (size_t)K + kt + sgran * 8],
                &As[(wv * 16) * 32]);
        #pragma unroll
        for (int i = 0; i < 2; ++i) {
            int row0 = wv * 32 + i * 16;
            async16(&W[(size_t)(row0 + srow_l) * K + kt + sgran * 8], &Bs[row0 * 32]);
        }
    };
    auto COMPUTE = [&](int buf) {
        unsigned short* As = smem + buf * 12288;
        unsigned short* Bs = As + 4096;
        short8_t af[4], bfr[4];
        const int gsw = g4 ^ ((r16 >> 1) & 3);
        #pragma unroll
        for (int m = 0; m < 4; ++m) {
            int row = wr * 64 + m * 16 + r16;
            af[m] = *reinterpret_cast<const short8_t*>(&As[row * 32 + gsw * 8]);
        }
        #pragma unroll
        for (int n = 0; n < 4; ++n) {
            int row = wc * 64 + n * 16 + r16;
            bfr[n] = *reinterpret_cast<const short8_t*>(&Bs[row * 32 + gsw * 8]);
        }
        #pragma unroll
        for (int m = 0; m < 4; ++m)
            #pragma unroll
            for (int n = 0; n < 4; ++n)
                acc[m][n] = __builtin_amdgcn_mfma_f32_16x16x32_bf16(af[m], bfr[n], acc[m][n], 0, 0, 0);
    };

    const int nk = K >> 5;
    STAGE(0, 0);
    STAGE(1, 32);
    int cb = 0;
    for (int ks = 0; ks < nk; ++ks) {
        if (ks == nk - 1) { asm volatile("s_waitcnt vmcnt(0)" ::: "memory"); }
        else              { asm volatile("s_waitcnt vmcnt(3)" ::: "memory"); }
        __builtin_amdgcn_sched_barrier(0);
        asm volatile("s_barrier" ::: "memory");
        if (ks + 2 < nk) {
            int sb = cb + 2; if (sb >= 3) sb -= 3;
            STAGE(sb, (ks + 2) << 5);
        }
        __builtin_amdgcn_sched_barrier(0);
        COMPUTE(cb);
        cb = (cb == 2) ? 0 : cb + 1;
    }
    __builtin_amdgcn_sched_barrier(0);
    asm volatile("s_barrier" ::: "memory");

    float bv[4];
    #pragma unroll
    for (int n = 0; n < 4; ++n) bv[n] = bias[wc * 64 + n * 16 + r16];
    float* psum  = reinterpret_cast<float*>(smem + 19456);   // [128][4]
    float* psq   = psum + 512;                               // [128][4]
    float* stats = psq + 512;                                // [128][2]
    #pragma unroll
    for (int m = 0; m < 4; ++m) {
        #pragma unroll
        for (int r = 0; r < 4; ++r) {
            float s = 0.f, s2 = 0.f;
            #pragma unroll
            for (int n = 0; n < 4; ++n) {
                float v = acc[m][n][r] + bv[n];
                s += v; s2 += v * v;
            }
            s  += __shfl_xor(s, 1);  s  += __shfl_xor(s, 2);
            s  += __shfl_xor(s, 4);  s  += __shfl_xor(s, 8);
            s2 += __shfl_xor(s2, 1); s2 += __shfl_xor(s2, 2);
            s2 += __shfl_xor(s2, 4); s2 += __shfl_xor(s2, 8);
            if (r16 == 0) {
                int row = wr * 64 + m * 16 + g4 * 4 + r;
                psum[row * 4 + wc] = s;
                psq[row * 4 + wc]  = s2;
            }
        }
    }
    __syncthreads();
    if (tid < 128) {
        f32x4 a = *reinterpret_cast<const f32x4*>(&psum[tid * 4]);
        f32x4 b = *reinterpret_cast<const f32x4*>(&psq[tid * 4]);
        float mu  = (a[0] + a[1] + a[2] + a[3]) * 0.00390625f;
        float ex2 = (b[0] + b[1] + b[2] + b[3]) * 0.00390625f;
        stats[tid * 2]     = mu;
        stats[tid * 2 + 1] = rsqrtf(ex2 - mu * mu + 1e-5f);
    }
    __syncthreads();

    unsigned short* Cs = smem + wv * 2432;
    const int rbase = g4 * 4;
    const int srow = lane >> 3, scol = (lane & 7) * 8;
    const int gcol0 = wc * 64;
    f32x4 gm0 = *reinterpret_cast<const f32x4*>(&gamma[gcol0 + scol]);
    f32x4 gm1 = *reinterpret_cast<const f32x4*>(&gamma[gcol0 + scol + 4]);
    f32x4 bt0 = *reinterpret_cast<const f32x4*>(&beta[gcol0 + scol]);
    f32x4 bt1 = *reinterpret_cast<const f32x4*>(&beta[gcol0 + scol + 4]);
    #pragma unroll
    for (int p = 0; p < 2; ++p) {
        #pragma unroll
        for (int n = 0; n < 4; ++n)
            #pragma unroll
            for (int m2 = 0; m2 < 2; ++m2)
                #pragma unroll
                for (int r = 0; r < 4; ++r)
                    Cs[(m2 * 16 + rbase + r) * 76 + n * 16 + r16] =
                        f2bf(acc[p * 2 + m2][n][r] + bv[n]);
        #pragma unroll
        for (int rr = 0; rr < 4; ++rr) {
            int lr = rr * 8 + srow;
            int lrow = wr * 64 + p * 32 + lr;
            int grow = bm * 128 + lrow;
            size_t orow = SCATTER ? (size_t)win_row_to_token(grow) : (size_t)grow;
            float mu  = stats[lrow * 2];
            float inv = stats[lrow * 2 + 1];
            short8_t cv = *reinterpret_cast<const short8_t*>(&Cs[lr * 76 + scol]);
            short8_t rv = *reinterpret_cast<const short8_t*>(&resid[orow * 256 + gcol0 + scol]);
            float o[8];
            #pragma unroll
            for (int e = 0; e < 8; ++e) {
                float g = (e < 4) ? gm0[e] : gm1[e - 4];
                float bb = (e < 4) ? bt0[e] : bt1[e - 4];
                o[e] = bf2f((unsigned short)rv[e])
                     + (bf2f((unsigned short)cv[e]) - mu) * inv * g + bb;
            }
            if (OUT_F32) {
                float* outp = (float*)Cv + orow * 256 + gcol0 + scol;
                f32x4 o0, o1;
                #pragma unroll
                for (int e = 0; e < 4; ++e) { o0[e] = o[e]; o1[e] = o[e + 4]; }
                *reinterpret_cast<f32x4*>(outp)     = o0;
                *reinterpret_cast<f32x4*>(outp + 4) = o1;
            } else {
                unsigned short* outp = (unsigned short*)Cv + orow * 256 + gcol0 + scol;
                short8_t ov;
                #pragma unroll
                for (int e = 0; e < 8; ++e) ov[e] = (short)f2bf(o[e]);
                *reinterpret_cast<short8_t*>(outp) = ov;
            }
        }
    }
}

// ---------------- attention: one WAVE per (window, head), swapped-QK MFMA ----------------
// QK computed as mfma(K, Q) -> lane holds S^T fragments: j = ji*16+g4*4+r (in regs),
// i = mi*16+r16. j-reduction = lane-local 16-reg tree + 2 shfls (vs 8 shfls/row).
__global__ __launch_bounds__(64) void attn_kernel(
    const unsigned short* __restrict__ qkv, const float* __restrict__ scales,
    const float* __restrict__ rpbf, unsigned short* __restrict__ out)
{
    constexpr int PO = 0;        // 64 x 72 ushorts
    constexpr int VO = 4608;     // 32 x 72 ushorts
    __shared__ unsigned short lds[6912];

    const int blk = blockIdx.x;
    const int h = blk & 7, wb = blk >> 3;
    const int lane = threadIdx.x;
    const int r16 = lane & 15, g4 = lane >> 4;

    const int wq = wb & 7, hb = (wb >> 3) & 7, dd = (wb >> 6) & 7, bb2 = wb >> 9;
    const int tok_base = ((bb2 * 8 + dd) * 56 + hb * 7) * 56 + wq * 7;
    const float sc = scales[h];

    // zero V^T j-pad (j 48..63)
    {
        short8_t z = {};
        int d = lane >> 1, j0 = 48 + (lane & 1) * 8;
        *reinterpret_cast<short8_t*>(&lds[VO + d * 72 + j0]) = z;
    }
    // stage V^T via register transpose: short8 row loads -> 8 scalar LDS writes
    for (int c = lane; c < 196; c += 64) {
        int j = c >> 2, gi = c & 3;
        int tok = tok_base + (j / 7) * 56 + (j % 7);
        short8_t raw = *reinterpret_cast<const short8_t*>(
            qkv + (size_t)tok * 768 + 512 + h * 32 + gi * 8);
        #pragma unroll
        for (int e = 0; e < 8; ++e)
            lds[VO + (gi * 8 + e) * 72 + j] = (unsigned short)raw[e];
    }

    // Q/K fragments: direct global load + cross-lane l2norm
    short8_t qf[4], kf[4];
    #pragma unroll
    for (int sel = 0; sel < 2; ++sel) {
        #pragma unroll
        for (int mi = 0; mi < 4; ++mi) {
            int row = mi * 16 + r16;
            int tok = tok_base + (row / 7) * 56 + (row % 7);
            short8_t raw = *reinterpret_cast<const short8_t*>(
                qkv + (size_t)tok * 768 + sel * 256 + h * 32 + g4 * 8);
            float f[8]; float ss = 0.f;
            #pragma unroll
            for (int e = 0; e < 8; ++e) { f[e] = bf2f((unsigned short)raw[e]); ss += f[e] * f[e]; }
            ss += __shfl_xor(ss, 16); ss += __shfl_xor(ss, 32);
            float inv = 1.f / fmaxf(sqrtf(ss), 1e-12f);
            if (sel == 0) inv *= sc;
            short8_t o;
            #pragma unroll
            for (int e = 0; e < 8; ++e) o[e] = (short)f2bf(f[e] * inv);
            if (sel == 0) qf[mi] = o; else kf[mi] = o;
        }
    }
    __syncthreads();   // V^T staged

    // ---- QK^T swapped: accT[ji][mi] = K_tile(ji) x Q_tile(mi)^T ----
    f32x4 accT[4][4] = {};
    __builtin_amdgcn_s_setprio(1);
    #pragma unroll
    for (int ji = 0; ji < 4; ++ji)
        #pragma unroll
        for (int mi = 0; mi < 4; ++mi)
            accT[ji][mi] = __builtin_amdgcn_mfma_f32_16x16x32_bf16(kf[ji], qf[mi], accT[ji][mi], 0, 0, 0);
    __builtin_amdgcn_s_setprio(0);

    // ---- prefetch rpb fragments (layout matches: [mi][ji][r16][g4][r]) ----
    const float* rbf = rpbf + h * 4096 + r16 * 16 + g4 * 4;
    f32x4 rbv[4][4];
    #pragma unroll
    for (int mi = 0; mi < 4; ++mi)
        #pragma unroll
        for (int ji = 0; ji < 4; ++ji)
            rbv[mi][ji] = *reinterpret_cast<const f32x4*>(&rbf[(mi * 4 + ji) * 256]);

    // ---- softmax over j (lane-local + 2 shfls), P -> LDS bf16 [i][j] ----
    #pragma unroll
    for (int mi = 0; mi < 4; ++mi) {
        const int i = mi * 16 + r16;
        float m = -1e30f;
        #pragma unroll
        for (int ji = 0; ji < 4; ++ji)
            #pragma unroll
            for (int r = 0; r < 4; ++r) {
                int j = ji * 16 + (g4 << 2) + r;
                float v = accT[ji][mi][r] + rbv[mi][ji][r];
                v = (j < 49) ? v : -1e30f;
                accT[ji][mi][r] = v;
                m = fmaxf(m, v);
            }
        m = fmaxf(m, __shfl_xor(m, 16));
        m = fmaxf(m, __shfl_xor(m, 32));
        float sum = 0.f;
        #pragma unroll
        for (int ji = 0; ji < 4; ++ji)
            #pragma unroll
            for (int r = 0; r < 4; ++r) {
                float v = accT[ji][mi][r];
                float e = (v > -1e29f) ? __expf(v - m) : 0.f;
                accT[ji][mi][r] = e;
                sum += e;
            }
        sum += __shfl_xor(sum, 16);
        sum += __shfl_xor(sum, 32);
        float rinv = 1.f / sum;
        #pragma unroll
        for (int ji = 0; ji < 4; ++ji)
            #pragma unroll
            for (int r = 0; r < 4; ++r)
                lds[PO + i * 72 + ji * 16 + (g4 << 2) + r] = f2bf(accT[ji][mi][r] * rinv);
    }
    __syncthreads();   // P writes drained before ds_read

    // ---- PV: setprio(1) cluster (unchanged layout: P[i][j], V^T[d][j]) ----
    f32x4 acc2[4][2] = {};
    __builtin_amdgcn_s_setprio(1);
    #pragma unroll
    for (int ks = 0; ks < 2; ++ks) {
        short8_t pf[4], vf[2];
        int ko = ks * 32 + g4 * 8;
        #pragma unroll
        for (int mi = 0; mi < 4; ++mi)
            pf[mi] = *reinterpret_cast<const short8_t*>(&lds[PO + (mi * 16 + r16) * 72 + ko]);
        #pragma unroll
        for (int ni = 0; ni < 2; ++ni)
            vf[ni] = *reinterpret_cast<const short8_t*>(&lds[VO + (ni * 16 + r16) * 72 + ko]);
        #pragma unroll
        for (int mi = 0; mi < 4; ++mi)
            #pragma unroll
            for (int ni = 0; ni < 2; ++ni)
                acc2[mi][ni] = __builtin_amdgcn_mfma_f32_16x16x32_bf16(pf[mi], vf[ni], acc2[mi][ni], 0, 0, 0);
    }
    __builtin_amdgcn_s_setprio(0);

    #pragma unroll
    for (int mi = 0; mi < 4; ++mi)
        #pragma unroll
        for (int r = 0; r < 4; ++r) {
            int i = mi * 16 + g4 * 4 + r;
            if (i < 49) {
                size_t ob = (size_t)(wb * 49 + i) * 256 + h * 32;
                out[ob + r16]      = f2bf(acc2[mi][0][r]);
                out[ob + 16 + r16] = f2bf(acc2[mi][1][r]);
            }
        }
}

extern "C" void kernel_launch(void* const* d_in, const int* in_sizes, int n_in,
                              void* d_out, int out_size, void* d_ws, size_t ws_size,
                              hipStream_t stream) {
    const float* x      = (const float*)d_in[0];
    const float* qkv_w  = (const float*)d_in[1];
    const float* q_bias = (const float*)d_in[2];
    const float* v_bias = (const float*)d_in[3];
    const float* lscale = (const float*)d_in[4];
    const float* cpb_w1 = (const float*)d_in[5];
    const float* cpb_b1 = (const float*)d_in[6];
    const float* cpb_w2 = (const float*)d_in[7];
    const float* proj_w = (const float*)d_in[8];
    const float* proj_b = (const float*)d_in[9];
    const float* n1g    = (const float*)d_in[10];
    const float* n1b    = (const float*)d_in[11];
    const float* fc1_w  = (const float*)d_in[12];
    const float* fc1_b  = (const float*)d_in[13];
    const float* fc2_w  = (const float*)d_in[14];
    const float* fc2_b  = (const float*)d_in[15];
    const float* n2g    = (const float*)d_in[16];
    const float* n2b    = (const float*)d_in[17];
    const float* rct    = (const float*)d_in[18];
    const int*   rpi    = (const int*)d_in[19];

    char* ws = (char*)d_ws;
    unsigned short* qkv    = (unsigned short*)(ws);
    unsigned short* hbuf   = (unsigned short*)(ws);
    unsigned short* attn_o = (unsigned short*)(ws + 154140672);
    unsigned short* xb     = (unsigned short*)(ws + 205520896);
    unsigned short* x1     = (unsigned short*)(ws + 205520896);
    unsigned short* wqkv   = (unsigned short*)(ws + 308281344);
    unsigned short* wproj  = (unsigned short*)(ws + 308674560);
    unsigned short* wfc1   = (unsigned short*)(ws + 308805632);
    unsigned short* wfc2   = (unsigned short*)(ws + 309329920);
    float*          rpbf   = (float*)(ws + 309854208);
    float*          scales = (float*)(ws + 310378496);
    float*          qkvb   = (float*)(ws + 310378528);
    float*          tableg = (float*)(ws + 310381600);

    const int M = 100352;

    conv_kernel<<<2048, 256, 0, stream>>>(x, xb, 25690112 / 4);
    conv4_kernel<<<768, 256, 0, stream>>>(qkv_w, wqkv, 49152,
                                          proj_w, wproj, 16384,
                                          fc1_w, wfc1, 65536,
                                          fc2_w, wfc2, 65536);
    prep_table_kernel<<<169, 256, 0, stream>>>(cpb_w1, cpb_b1, cpb_w2, rct, tableg);
    prep_expand_kernel<<<128, 256, 0, stream>>>(lscale, q_bias, v_bias, rpi, tableg,
                                                scales, rpbf, qkvb);
    // qkv = xb @ wqkv^T + qkv_bias   (128x128 tiles: 784 x 6)
    gemm2_kernel<0><<<4704, 512, 0, stream>>>(xb, wqkv, qkvb, qkv, M, 768, 256, 6);
    // attention -> window-ordered (Bw*49, 256)
    attn_kernel<<<16384, 64, 0, stream>>>(qkv, scales, rpbf, attn_o);
    // x1 = xb + LN(attn_o @ wproj^T + proj_b)  [fused, scatter to natural order]
    gemm_ln_kernel<1, 0><<<784, 512, 0, stream>>>(attn_o, wproj, proj_b, xb, n1g, n1b,
                                                  x1, M, 256);
    // h = gelu(x1 @ wfc1^T + fc1_b)   (128x128 tiles: 784 x 8)
    gemm2_kernel<1><<<6272, 512, 0, stream>>>(x1, wfc1, fc1_b, hbuf, M, 1024, 256, 8);
    // out = x1 + LN(h @ wfc2^T + fc2_b)  [fused, f32 output]
    gemm_ln_kernel<0, 1><<<784, 512, 0, stream>>>(hbuf, wfc2, fc2_b, x1, n2g, n2b,
                                                  d_out, M, 1024);
}

// Round 24
// 419.371 us; speedup vs baseline: 1.0673x; 1.0168x over previous
//
#include <hip/hip_runtime.h>
#include <hip/hip_bf16.h>

typedef __attribute__((ext_vector_type(8))) short short8_t;
typedef __attribute__((ext_vector_type(4))) float f32x4;

__device__ __forceinline__ float bf2f(unsigned short u) {
    return __uint_as_float(((unsigned)u) << 16);
}
__device__ __forceinline__ unsigned short f2bf(float f) {
    __hip_bfloat16 h = __float2bfloat16(f);
    return *reinterpret_cast<unsigned short*>(&h);
}

// exact-GELU via Abramowitz-Stegun 7.1.26 erf (|err| <= 1.5e-7), branch-free.
__device__ __forceinline__ float fast_gelu(float v) {
    float ax = fabsf(v) * 0.70710678118f;
    float t  = __builtin_amdgcn_rcpf(1.f + 0.3275911f * ax);
    float poly = t * (0.254829592f + t * (-0.284496736f + t * (1.421413741f
               + t * (-1.453152027f + t * 1.061405429f))));
    float e  = __expf(-ax * ax);
    float er = 1.f - poly * e;                 // erf(ax), ax >= 0
    float s  = (v >= 0.f) ? er : -er;
    return 0.5f * v * (1.f + s);
}

// async global->LDS, 16B per lane; LDS dest = wave-uniform base + lane*16
__device__ __forceinline__ void async16(const unsigned short* g, unsigned short* l) {
    __builtin_amdgcn_global_load_lds(
        (const __attribute__((address_space(1))) unsigned int*)g,
        (__attribute__((address_space(3))) unsigned int*)l,
        16, 0, 0);
}

// window-order row r (r = wb*49 + n) -> natural token index
__device__ __forceinline__ int win_row_to_token(int r) {
    int wb = r / 49, n = r - wb * 49;
    int wq = wb & 7, hb = (wb >> 3) & 7, d = (wb >> 6) & 7, b = wb >> 9;
    int hh = n / 7, ww2 = n - hh * 7;
    return ((b * 8 + d) * 56 + hb * 7 + hh) * 56 + wq * 7 + ww2;
}

// ---------------- f32 -> bf16 bulk convert ----------------
__global__ __launch_bounds__(256) void conv_kernel(
    const float* __restrict__ src, unsigned short* __restrict__ dst, int n4)
{
    int stride = gridDim.x * 256;
    for (int i = blockIdx.x * 256 + threadIdx.x; i < n4; i += stride) {
        float4 v = *reinterpret_cast<const float4*>(&src[(size_t)i * 4]);
        short4 o;
        o.x = (short)f2bf(v.x); o.y = (short)f2bf(v.y);
        o.z = (short)f2bf(v.z); o.w = (short)f2bf(v.w);
        *reinterpret_cast<short4*>(&dst[(size_t)i * 4]) = o;
    }
}

// 4 weight tensors in one dispatch (vec4 counts)
__global__ __launch_bounds__(256) void conv4_kernel(
    const float* __restrict__ s0, unsigned short* __restrict__ d0, int n0,
    const float* __restrict__ s1, unsigned short* __restrict__ d1, int n1,
    const float* __restrict__ s2, unsigned short* __restrict__ d2, int n2,
    const float* __restrict__ s3, unsigned short* __restrict__ d3, int n3)
{
    int stride = gridDim.x * 256;
    int total = n0 + n1 + n2 + n3;
    for (int i = blockIdx.x * 256 + threadIdx.x; i < total; i += stride) {
        const float* s; unsigned short* d; int j = i;
        if (j < n0) { s = s0; d = d0; }
        else if ((j -= n0) < n1) { s = s1; d = d1; }
        else if ((j -= n1) < n2) { s = s2; d = d2; }
        else { j -= n2; s = s3; d = d3; }
        float4 v = *reinterpret_cast<const float4*>(&s[(size_t)j * 4]);
        short4 o;
        o.x = (short)f2bf(v.x); o.y = (short)f2bf(v.y);
        o.z = (short)f2bf(v.z); o.w = (short)f2bf(v.w);
        *reinterpret_cast<short4*>(&d[(size_t)j * 4]) = o;
    }
}

// ---------------- prep stage 1: CPB-MLP table, one block per table row ----------------
__global__ __launch_bounds__(256) void prep_table_kernel(
    const float* __restrict__ w1, const float* __restrict__ b1,
    const float* __restrict__ w2, const float* __restrict__ tabin,
    float* __restrict__ tableg)
{
    const int i = blockIdx.x;          // 0..168
    const int t = threadIdx.x;
    const float c0 = tabin[i * 3], c1 = tabin[i * 3 + 1], c2 = tabin[i * 3 + 2];
    float part[8] = {0.f, 0.f, 0.f, 0.f, 0.f, 0.f, 0.f, 0.f};
    for (int j = t; j < 512; j += 256) {
        float hv = fmaxf(c0 * w1[j * 3] + c1 * w1[j * 3 + 1] + c2 * w1[j * 3 + 2] + b1[j], 0.f);
        #pragma unroll
        for (int h = 0; h < 8; ++h) part[h] += hv * w2[h * 512 + j];
    }
    #pragma unroll
    for (int h = 0; h < 8; ++h) {
        float v = part[h];
        v += __shfl_xor(v, 1);  v += __shfl_xor(v, 2);  v += __shfl_xor(v, 4);
        v += __shfl_xor(v, 8);  v += __shfl_xor(v, 16); v += __shfl_xor(v, 32);
        part[h] = v;
    }
    __shared__ float red[4][8];
    const int wv = t >> 6, lane = t & 63;
    if (lane == 0) {
        #pragma unroll
        for (int h = 0; h < 8; ++h) red[wv][h] = part[h];
    }
    __syncthreads();
    if (t < 8) tableg[i * 8 + t] = red[0][t] + red[1][t] + red[2][t] + red[3][t];
}

// ---------------- prep stage 2: scales, qkv bias, rpbf expansion ----------------
// rpbf layout [h][mi][ji][r16][g4][r] = rpb[i][j] with i = mi*16 + r16,
// j = ji*16 + g4*4 + r  (matches swapped-QK S^T fragment orientation).
__global__ __launch_bounds__(256) void prep_expand_kernel(
    const float* __restrict__ logit_scale,
    const float* __restrict__ qb, const float* __restrict__ vb,
    const int* __restrict__ rpi, const float* __restrict__ tableg,
    float* __restrict__ scales, float* __restrict__ rpbf,
    float* __restrict__ qkvb)
{
    const int stride = gridDim.x * 256;
    const int gt = blockIdx.x * 256 + threadIdx.x;
    if (gt < 8) scales[gt] = expf(fminf(logit_scale[gt], 4.6051702f)); // ln(100)
    for (int i = gt; i < 768; i += stride) {
        float o;
        if (i < 256) o = qb[i];
        else if (i < 512) o = 0.f;
        else o = vb[i - 512];
        qkvb[i] = o;
    }
    for (int e = gt; e < 32768; e += stride) {
        int h = e >> 12, rem = e & 4095;
        int mi = rem >> 10, ji = (rem >> 8) & 3;
        int r16 = (rem >> 4) & 15, g4 = (rem >> 2) & 3, r = rem & 3;
        int i = mi * 16 + r16, j = ji * 16 + g4 * 4 + r;   // swapped orientation
        float val = 0.f;
        if (i < 49 && j < 49) {
            float xv = tableg[rpi[i * 49 + j] * 8 + h];
            val = 16.f / (1.f + expf(-xv));
        }
        rpbf[e] = val;
    }
}

// ---------------- GEMM: 128x128 tile, 8 waves x (64x32), 3-buffer pipeline ----------------
template<int ACT>
__global__ __launch_bounds__(512, 6) void gemm2_kernel(
    const unsigned short* __restrict__ A, const unsigned short* __restrict__ W,
    const float* __restrict__ bias, unsigned short* __restrict__ C,
    int M, int N, int K, int ntn)
{
    __shared__ unsigned short smem[24576];   // 48KB: 3 x (As 128x32 + Bs 128x32)
    const int tid = threadIdx.x;
    const int lane = tid & 63, wv = tid >> 6;
    const int wr = wv >> 2, wc = wv & 3;
    const int nwg = gridDim.x;
    const int virt = (blockIdx.x & 7) * (nwg >> 3) + (blockIdx.x >> 3);
    const int bn = virt % ntn, bm = virt / ntn;
    const size_t arow0 = (size_t)bm * 128;
    const size_t brow0 = (size_t)bn * 128;
    const int r16 = lane & 15, g4 = lane >> 4;
    const int srow_l = lane >> 2;
    const int sgran  = (lane & 3) ^ ((srow_l >> 1) & 3);
    f32x4 acc[4][2] = {};

    auto STAGE = [&](int buf, int kt) {      // 2 loads per thread
        unsigned short* As = smem + buf * 8192;
        unsigned short* Bs = As + 4096;
        int row0 = wv * 16;
        async16(&A[(arow0 + row0 + srow_l) * (size_t)K + kt + sgran * 8], &As[row0 * 32]);
        async16(&W[(brow0 + row0 + srow_l) * (size_t)K + kt + sgran * 8], &Bs[row0 * 32]);
    };
    auto COMPUTE = [&](int buf) {
        unsigned short* As = smem + buf * 8192;
        unsigned short* Bs = As + 4096;
        short8_t af[4], bfr[2];
        const int gsw = g4 ^ ((r16 >> 1) & 3);
        #pragma unroll
        for (int m = 0; m < 4; ++m) {
            int row = wr * 64 + m * 16 + r16;
            af[m] = *reinterpret_cast<const short8_t*>(&As[row * 32 + gsw * 8]);
        }
        #pragma unroll
        for (int n = 0; n < 2; ++n) {
            int row = wc * 32 + n * 16 + r16;
            bfr[n] = *reinterpret_cast<const short8_t*>(&Bs[row * 32 + gsw * 8]);
        }
        #pragma unroll
        for (int m = 0; m < 4; ++m)
            #pragma unroll
            for (int n = 0; n < 2; ++n)
                acc[m][n] = __builtin_amdgcn_mfma_f32_16x16x32_bf16(af[m], bfr[n], acc[m][n], 0, 0, 0);
    };

    const int nk = K >> 5;
    STAGE(0, 0);
    STAGE(1, 32);
    int cb = 0;
    for (int ks = 0; ks < nk; ++ks) {
        if (ks == nk - 1) { asm volatile("s_waitcnt vmcnt(0)" ::: "memory"); }
        else              { asm volatile("s_waitcnt vmcnt(2)" ::: "memory"); }
        __builtin_amdgcn_sched_barrier(0);
        asm volatile("s_barrier" ::: "memory");
        if (ks + 2 < nk) {
            int sb = cb + 2; if (sb >= 3) sb -= 3;
            STAGE(sb, (ks + 2) << 5);
        }
        __builtin_amdgcn_sched_barrier(0);
        COMPUTE(cb);
        cb = (cb == 2) ? 0 : cb + 1;
    }
    __builtin_amdgcn_sched_barrier(0);
    asm volatile("s_barrier" ::: "memory");  // LDS dead; epilogue overlays

    // ---- epilogue: per-wave 64x36 transpose -> coalesced stores ----
    unsigned short* Cs = smem + wv * 2304;   // 64 x 36 ushorts per wave
    const int rbase = g4 * 4;
    const int srow = lane >> 2, scol = (lane & 3) * 8;
    const int gcol0 = bn * 128 + wc * 32;
    #pragma unroll
    for (int n = 0; n < 2; ++n) {
        float bv = bias[gcol0 + n * 16 + r16];
        #pragma unroll
        for (int m = 0; m < 4; ++m)
            #pragma unroll
            for (int r = 0; r < 4; ++r) {
                float v = acc[m][n][r] + bv;
                if (ACT == 1) v = fast_gelu(v);
                Cs[(m * 16 + rbase + r) * 36 + n * 16 + r16] = f2bf(v);
            }
    }
    #pragma unroll
    for (int pass = 0; pass < 4; ++pass) {
        int lr = pass * 16 + srow;
        int grow = bm * 128 + wr * 64 + lr;
        short8_t vv = *reinterpret_cast<const short8_t*>(&Cs[lr * 36 + scol]);
        *reinterpret_cast<short8_t*>(&C[(size_t)grow * N + gcol0 + scol]) = vv;
    }
}

// ---------------- fused GEMM + residual + LayerNorm (N=256), 3-buffer pipeline ----------
template<int SCATTER, int OUT_F32>
__global__ __launch_bounds__(512) void gemm_ln_kernel(
    const unsigned short* __restrict__ A, const unsigned short* __restrict__ W,
    const float* __restrict__ bias, const unsigned short* __restrict__ resid,
    const float* __restrict__ gamma, const float* __restrict__ beta,
    void* __restrict__ Cv, int M, int K)
{
    __shared__ unsigned short smem[36864];   // 72KB, 3 buffers
    const int tid = threadIdx.x;
    const int lane = tid & 63, wv = tid >> 6;
    const int wr = wv >> 2, wc = wv & 3;
    const int nwg = gridDim.x;
    const int bm = (blockIdx.x & 7) * (nwg >> 3) + (blockIdx.x >> 3);
    const size_t arow0 = (size_t)bm * 128;
    const int r16 = lane & 15, g4 = lane >> 4;
    const int srow_l = lane >> 2;
    const int sgran = (lane & 3) ^ ((srow_l >> 1) & 3);
    f32x4 acc[4][4] = {};

    auto STAGE = [&](int buf, int kt) {
        unsigned short* As = smem + buf * 12288;
        unsigned short* Bs = As + 4096;
        async16(&A[(arow0 + wv * 16 + srow_l) * (size_t)K + kt + sgran * 8],
                &As[(wv * 16) * 32]);
        #pragma unroll
        for (int i = 0; i < 2; ++i) {
            int row0 = wv * 32 + i * 16;
            async16(&W[(size_t)(row0 + srow_l) * K + kt + sgran * 8], &Bs[row0 * 32]);
        }
    };
    auto COMPUTE = [&](int buf) {
        unsigned short* As = smem + buf * 12288;
        unsigned short* Bs = As + 4096;
        short8_t af[4], bfr[4];
        const int gsw = g4 ^ ((r16 >> 1) & 3);
        #pragma unroll
        for (int m = 0; m < 4; ++m) {
            int row = wr * 64 + m * 16 + r16;
            af[m] = *reinterpret_cast<const short8_t*>(&As[row * 32 + gsw * 8]);
        }
        #pragma unroll
        for (int n = 0; n < 4; ++n) {
            int row = wc * 64 + n * 16 + r16;
            bfr[n] = *reinterpret_cast<const short8_t*>(&Bs[row * 32 + gsw * 8]);
        }
        #pragma unroll
        for (int m = 0; m < 4; ++m)
            #pragma unroll
            for (int n = 0; n < 4; ++n)
                acc[m][n] = __builtin_amdgcn_mfma_f32_16x16x32_bf16(af[m], bfr[n], acc[m][n], 0, 0, 0);
    };

    const int nk = K >> 5;
    STAGE(0, 0);
    STAGE(1, 32);
    int cb = 0;
    for (int ks = 0; ks < nk; ++ks) {
        if (ks == nk - 1) { asm volatile("s_waitcnt vmcnt(0)" ::: "memory"); }
        else              { asm volatile("s_waitcnt vmcnt(3)" ::: "memory"); }
        __builtin_amdgcn_sched_barrier(0);
        asm volatile("s_barrier" ::: "memory");
        if (ks + 2 < nk) {
            int sb = cb + 2; if (sb >= 3) sb -= 3;
            STAGE(sb, (ks + 2) << 5);
        }
        __builtin_amdgcn_sched_barrier(0);
        COMPUTE(cb);
        cb = (cb == 2) ? 0 : cb + 1;
    }
    __builtin_amdgcn_sched_barrier(0);
    asm volatile("s_barrier" ::: "memory");

    float bv[4];
    #pragma unroll
    for (int n = 0; n < 4; ++n) bv[n] = bias[wc * 64 + n * 16 + r16];
    float* psum  = reinterpret_cast<float*>(smem + 19456);   // [128][4]
    float* psq   = psum + 512;                               // [128][4]
    float* stats = psq + 512;                                // [128][2]
    #pragma unroll
    for (int m = 0; m < 4; ++m) {
        #pragma unroll
        for (int r = 0; r < 4; ++r) {
            float s = 0.f, s2 = 0.f;
            #pragma unroll
            for (int n = 0; n < 4; ++n) {
                float v = acc[m][n][r] + bv[n];
                s += v; s2 += v * v;
            }
            s  += __shfl_xor(s, 1);  s  += __shfl_xor(s, 2);
            s  += __shfl_xor(s, 4);  s  += __shfl_xor(s, 8);
            s2 += __shfl_xor(s2, 1); s2 += __shfl_xor(s2, 2);
            s2 += __shfl_xor(s2, 4); s2 += __shfl_xor(s2, 8);
            if (r16 == 0) {
                int row = wr * 64 + m * 16 + g4 * 4 + r;
                psum[row * 4 + wc] = s;
                psq[row * 4 + wc]  = s2;
            }
        }
    }
    __syncthreads();
    if (tid < 128) {
        f32x4 a = *reinterpret_cast<const f32x4*>(&psum[tid * 4]);
        f32x4 b = *reinterpret_cast<const f32x4*>(&psq[tid * 4]);
        float mu  = (a[0] + a[1] + a[2] + a[3]) * 0.00390625f;
        float ex2 = (b[0] + b[1] + b[2] + b[3]) * 0.00390625f;
        stats[tid * 2]     = mu;
        stats[tid * 2 + 1] = rsqrtf(ex2 - mu * mu + 1e-5f);
    }
    __syncthreads();

    unsigned short* Cs = smem + wv * 2432;
    const int rbase = g4 * 4;
    const int srow = lane >> 3, scol = (lane & 7) * 8;
    const int gcol0 = wc * 64;
    f32x4 gm0 = *reinterpret_cast<const f32x4*>(&gamma[gcol0 + scol]);
    f32x4 gm1 = *reinterpret_cast<const f32x4*>(&gamma[gcol0 + scol + 4]);
    f32x4 bt0 = *reinterpret_cast<const f32x4*>(&beta[gcol0 + scol]);
    f32x4 bt1 = *reinterpret_cast<const f32x4*>(&beta[gcol0 + scol + 4]);
    #pragma unroll
    for (int p = 0; p < 2; ++p) {
        #pragma unroll
        for (int n = 0; n < 4; ++n)
            #pragma unroll
            for (int m2 = 0; m2 < 2; ++m2)
                #pragma unroll
                for (int r = 0; r < 4; ++r)
                    Cs[(m2 * 16 + rbase + r) * 76 + n * 16 + r16] =
                        f2bf(acc[p * 2 + m2][n][r] + bv[n]);
        #pragma unroll
        for (int rr = 0; rr < 4; ++rr) {
            int lr = rr * 8 + srow;
            int lrow = wr * 64 + p * 32 + lr;
            int grow = bm * 128 + lrow;
            size_t orow = SCATTER ? (size_t)win_row_to_token(grow) : (size_t)grow;
            float mu  = stats[lrow * 2];
            float inv = stats[lrow * 2 + 1];
            short8_t cv = *reinterpret_cast<const short8_t*>(&Cs[lr * 76 + scol]);
            short8_t rv = *reinterpret_cast<const short8_t*>(&resid[orow * 256 + gcol0 + scol]);
            float o[8];
            #pragma unroll
            for (int e = 0; e < 8; ++e) {
                float g = (e < 4) ? gm0[e] : gm1[e - 4];
                float bb = (e < 4) ? bt0[e] : bt1[e - 4];
                o[e] = bf2f((unsigned short)rv[e])
                     + (bf2f((unsigned short)cv[e]) - mu) * inv * g + bb;
            }
            if (OUT_F32) {
                float* outp = (float*)Cv + orow * 256 + gcol0 + scol;
                f32x4 o0, o1;
                #pragma unroll
                for (int e = 0; e < 4; ++e) { o0[e] = o[e]; o1[e] = o[e + 4]; }
                *reinterpret_cast<f32x4*>(outp)     = o0;
                *reinterpret_cast<f32x4*>(outp + 4) = o1;
            } else {
                unsigned short* outp = (unsigned short*)Cv + orow * 256 + gcol0 + scol;
                short8_t ov;
                #pragma unroll
                for (int e = 0; e < 8; ++e) ov[e] = (short)f2bf(o[e]);
                *reinterpret_cast<short8_t*>(outp) = ov;
            }
        }
    }
}

// ---------------- attention: TWO (window,head) pairs per 128-thread block ----------------
// Wave wv handles pair blockIdx.x*2+wv with wave-local LDS partition (13824 B each).
// Per-wave code identical to r23 (swapped-QK softmax, direct Q/K loads, setprio).
__global__ __launch_bounds__(128) void attn_kernel(
    const unsigned short* __restrict__ qkv, const float* __restrict__ scales,
    const float* __restrict__ rpbf, unsigned short* __restrict__ out)
{
    constexpr int PO = 0;        // 64 x 72 ushorts
    constexpr int VO = 4608;     // 32 x 72 ushorts
    __shared__ unsigned short lds_all[13824];   // 2 x 6912 ushorts

    const int wv = threadIdx.x >> 6;
    const int lane = threadIdx.x & 63;
    unsigned short* lds = lds_all + wv * 6912;

    const int pair = blockIdx.x * 2 + wv;
    const int h = pair & 7, wb = pair >> 3;
    const int r16 = lane & 15, g4 = lane >> 4;

    const int wq = wb & 7, hb = (wb >> 3) & 7, dd = (wb >> 6) & 7, bb2 = wb >> 9;
    const int tok_base = ((bb2 * 8 + dd) * 56 + hb * 7) * 56 + wq * 7;
    const float sc = scales[h];

    // zero V^T j-pad (j 48..63)
    {
        short8_t z = {};
        int d = lane >> 1, j0 = 48 + (lane & 1) * 8;
        *reinterpret_cast<short8_t*>(&lds[VO + d * 72 + j0]) = z;
    }
    // stage V^T via register transpose: short8 row loads -> 8 scalar LDS writes
    for (int c = lane; c < 196; c += 64) {
        int j = c >> 2, gi = c & 3;
        int tok = tok_base + (j / 7) * 56 + (j % 7);
        short8_t raw = *reinterpret_cast<const short8_t*>(
            qkv + (size_t)tok * 768 + 512 + h * 32 + gi * 8);
        #pragma unroll
        for (int e = 0; e < 8; ++e)
            lds[VO + (gi * 8 + e) * 72 + j] = (unsigned short)raw[e];
    }

    // Q/K fragments: direct global load + cross-lane l2norm
    short8_t qf[4], kf[4];
    #pragma unroll
    for (int sel = 0; sel < 2; ++sel) {
        #pragma unroll
        for (int mi = 0; mi < 4; ++mi) {
            int row = mi * 16 + r16;
            int tok = tok_base + (row / 7) * 56 + (row % 7);
            short8_t raw = *reinterpret_cast<const short8_t*>(
                qkv + (size_t)tok * 768 + sel * 256 + h * 32 + g4 * 8);
            float f[8]; float ss = 0.f;
            #pragma unroll
            for (int e = 0; e < 8; ++e) { f[e] = bf2f((unsigned short)raw[e]); ss += f[e] * f[e]; }
            ss += __shfl_xor(ss, 16); ss += __shfl_xor(ss, 32);
            float inv = 1.f / fmaxf(sqrtf(ss), 1e-12f);
            if (sel == 0) inv *= sc;
            short8_t o;
            #pragma unroll
            for (int e = 0; e < 8; ++e) o[e] = (short)f2bf(f[e] * inv);
            if (sel == 0) qf[mi] = o; else kf[mi] = o;
        }
    }
    __syncthreads();   // V^T staged (both waves; equal-length work)

    // ---- QK^T swapped: accT[ji][mi] = K_tile(ji) x Q_tile(mi)^T ----
    f32x4 accT[4][4] = {};
    __builtin_amdgcn_s_setprio(1);
    #pragma unroll
    for (int ji = 0; ji < 4; ++ji)
        #pragma unroll
        for (int mi = 0; mi < 4; ++mi)
            accT[ji][mi] = __builtin_amdgcn_mfma_f32_16x16x32_bf16(kf[ji], qf[mi], accT[ji][mi], 0, 0, 0);
    __builtin_amdgcn_s_setprio(0);

    // ---- prefetch rpb fragments (layout matches: [mi][ji][r16][g4][r]) ----
    const float* rbf = rpbf + h * 4096 + r16 * 16 + g4 * 4;
    f32x4 rbv[4][4];
    #pragma unroll
    for (int mi = 0; mi < 4; ++mi)
        #pragma unroll
        for (int ji = 0; ji < 4; ++ji)
            rbv[mi][ji] = *reinterpret_cast<const f32x4*>(&rbf[(mi * 4 + ji) * 256]);

    // ---- softmax over j (lane-local + 2 shfls), P -> LDS bf16 [i][j] ----
    #pragma unroll
    for (int mi = 0; mi < 4; ++mi) {
        const int i = mi * 16 + r16;
        float m = -1e30f;
        #pragma unroll
        for (int ji = 0; ji < 4; ++ji)
            #pragma unroll
            for (int r = 0; r < 4; ++r) {
                int j = ji * 16 + (g4 << 2) + r;
                float v = accT[ji][mi][r] + rbv[mi][ji][r];
                v = (j < 49) ? v : -1e30f;
                accT[ji][mi][r] = v;
                m = fmaxf(m, v);
            }
        m = fmaxf(m, __shfl_xor(m, 16));
        m = fmaxf(m, __shfl_xor(m, 32));
        float sum = 0.f;
        #pragma unroll
        for (int ji = 0; ji < 4; ++ji)
            #pragma unroll
            for (int r = 0; r < 4; ++r) {
                float v = accT[ji][mi][r];
                float e = (v > -1e29f) ? __expf(v - m) : 0.f;
                accT[ji][mi][r] = e;
                sum += e;
            }
        sum += __shfl_xor(sum, 16);
        sum += __shfl_xor(sum, 32);
        float rinv = 1.f / sum;
        #pragma unroll
        for (int ji = 0; ji < 4; ++ji)
            #pragma unroll
            for (int r = 0; r < 4; ++r)
                lds[PO + i * 72 + ji * 16 + (g4 << 2) + r] = f2bf(accT[ji][mi][r] * rinv);
    }
    __syncthreads();   // P writes drained before ds_read

    // ---- PV: setprio(1) cluster (P[i][j], V^T[d][j]) ----
    f32x4 acc2[4][2] = {};
    __builtin_amdgcn_s_setprio(1);
    #pragma unroll
    for (int ks = 0; ks < 2; ++ks) {
        short8_t pf[4], vf[2];
        int ko = ks * 32 + g4 * 8;
        #pragma unroll
        for (int mi = 0; mi < 4; ++mi)
            pf[mi] = *reinterpret_cast<const short8_t*>(&lds[PO + (mi * 16 + r16) * 72 + ko]);
        #pragma unroll
        for (int ni = 0; ni < 2; ++ni)
            vf[ni] = *reinterpret_cast<const short8_t*>(&lds[VO + (ni * 16 + r16) * 72 + ko]);
        #pragma unroll
        for (int mi = 0; mi < 4; ++mi)
            #pragma unroll
            for (int ni = 0; ni < 2; ++ni)
                acc2[mi][ni] = __builtin_amdgcn_mfma_f32_16x16x32_bf16(pf[mi], vf[ni], acc2[mi][ni], 0, 0, 0);
    }
    __builtin_amdgcn_s_setprio(0);

    #pragma unroll
    for (int mi = 0; mi < 4; ++mi)
        #pragma unroll
        for (int r = 0; r < 4; ++r) {
            int i = mi * 16 + g4 * 4 + r;
            if (i < 49) {
                size_t ob = (size_t)(wb * 49 + i) * 256 + h * 32;
                out[ob + r16]      = f2bf(acc2[mi][0][r]);
                out[ob + 16 + r16] = f2bf(acc2[mi][1][r]);
            }
        }
}

extern "C" void kernel_launch(void* const* d_in, const int* in_sizes, int n_in,
                              void* d_out, int out_size, void* d_ws, size_t ws_size,
                              hipStream_t stream) {
    const float* x      = (const float*)d_in[0];
    const float* qkv_w  = (const float*)d_in[1];
    const float* q_bias = (const float*)d_in[2];
    const float* v_bias = (const float*)d_in[3];
    const float* lscale = (const float*)d_in[4];
    const float* cpb_w1 = (const float*)d_in[5];
    const float* cpb_b1 = (const float*)d_in[6];
    const float* cpb_w2 = (const float*)d_in[7];
    const float* proj_w = (const float*)d_in[8];
    const float* proj_b = (const float*)d_in[9];
    const float* n1g    = (const float*)d_in[10];
    const float* n1b    = (const float*)d_in[11];
    const float* fc1_w  = (const float*)d_in[12];
    const float* fc1_b  = (const float*)d_in[13];
    const float* fc2_w  = (const float*)d_in[14];
    const float* fc2_b  = (const float*)d_in[15];
    const float* n2g    = (const float*)d_in[16];
    const float* n2b    = (const float*)d_in[17];
    const float* rct    = (const float*)d_in[18];
    const int*   rpi    = (const int*)d_in[19];

    char* ws = (char*)d_ws;
    unsigned short* qkv    = (unsigned short*)(ws);
    unsigned short* hbuf   = (unsigned short*)(ws);
    unsigned short* attn_o = (unsigned short*)(ws + 154140672);
    unsigned short* xb     = (unsigned short*)(ws + 205520896);
    unsigned short* x1     = (unsigned short*)(ws + 205520896);
    unsigned short* wqkv   = (unsigned short*)(ws + 308281344);
    unsigned short* wproj  = (unsigned short*)(ws + 308674560);
    unsigned short* wfc1   = (unsigned short*)(ws + 308805632);
    unsigned short* wfc2   = (unsigned short*)(ws + 309329920);
    float*          rpbf   = (float*)(ws + 309854208);
    float*          scales = (float*)(ws + 310378496);
    float*          qkvb   = (float*)(ws + 310378528);
    float*          tableg = (float*)(ws + 310381600);

    const int M = 100352;

    conv_kernel<<<2048, 256, 0, stream>>>(x, xb, 25690112 / 4);
    conv4_kernel<<<768, 256, 0, stream>>>(qkv_w, wqkv, 49152,
                                          proj_w, wproj, 16384,
                                          fc1_w, wfc1, 65536,
                                          fc2_w, wfc2, 65536);
    prep_table_kernel<<<169, 256, 0, stream>>>(cpb_w1, cpb_b1, cpb_w2, rct, tableg);
    prep_expand_kernel<<<128, 256, 0, stream>>>(lscale, q_bias, v_bias, rpi, tableg,
                                                scales, rpbf, qkvb);
    // qkv = xb @ wqkv^T + qkv_bias   (128x128 tiles: 784 x 6)
    gemm2_kernel<0><<<4704, 512, 0, stream>>>(xb, wqkv, qkvb, qkv, M, 768, 256, 6);
    // attention: 2 (window,head) pairs per block -> window-ordered (Bw*49, 256)
    attn_kernel<<<8192, 128, 0, stream>>>(qkv, scales, rpbf, attn_o);
    // x1 = xb + LN(attn_o @ wproj^T + proj_b)  [fused, scatter to natural order]
    gemm_ln_kernel<1, 0><<<784, 512, 0, stream>>>(attn_o, wproj, proj_b, xb, n1g, n1b,
                                                  x1, M, 256);
    // h = gelu(x1 @ wfc1^T + fc1_b)   (128x128 tiles: 784 x 8)
    gemm2_kernel<1><<<6272, 512, 0, stream>>>(x1, wfc1, fc1_b, hbuf, M, 1024, 256, 8);
    // out = x1 + LN(h @ wfc2^T + fc2_b)  [fused, f32 output]
    gemm_ln_kernel<0, 1><<<784, 512, 0, stream>>>(hbuf, wfc2, fc2_b, x1, n2g, n2b,
                                                  d_out, M, 1024);
}

// Round 25
// 416.193 us; speedup vs baseline: 1.0754x; 1.0076x over previous
//
#include <hip/hip_runtime.h>
#include <hip/hip_bf16.h>

typedef __attribute__((ext_vector_type(8))) short short8_t;
typedef __attribute__((ext_vector_type(4))) float f32x4;

__device__ __forceinline__ float bf2f(unsigned short u) {
    return __uint_as_float(((unsigned)u) << 16);
}
__device__ __forceinline__ unsigned short f2bf(float f) {
    __hip_bfloat16 h = __float2bfloat16(f);
    return *reinterpret_cast<unsigned short*>(&h);
}

// exact-GELU via Abramowitz-Stegun 7.1.26 erf (|err| <= 1.5e-7), branch-free.
__device__ __forceinline__ float fast_gelu(float v) {
    float ax = fabsf(v) * 0.70710678118f;
    float t  = __builtin_amdgcn_rcpf(1.f + 0.3275911f * ax);
    float poly = t * (0.254829592f + t * (-0.284496736f + t * (1.421413741f
               + t * (-1.453152027f + t * 1.061405429f))));
    float e  = __expf(-ax * ax);
    float er = 1.f - poly * e;                 // erf(ax), ax >= 0
    float s  = (v >= 0.f) ? er : -er;
    return 0.5f * v * (1.f + s);
}

// async global->LDS, 16B per lane; LDS dest = wave-uniform base + lane*16
__device__ __forceinline__ void async16(const unsigned short* g, unsigned short* l) {
    __builtin_amdgcn_global_load_lds(
        (const __attribute__((address_space(1))) unsigned int*)g,
        (__attribute__((address_space(3))) unsigned int*)l,
        16, 0, 0);
}

// window-order row r (r = wb*49 + n) -> natural token index
__device__ __forceinline__ int win_row_to_token(int r) {
    int wb = r / 49, n = r - wb * 49;
    int wq = wb & 7, hb = (wb >> 3) & 7, d = (wb >> 6) & 7, b = wb >> 9;
    int hh = n / 7, ww2 = n - hh * 7;
    return ((b * 8 + d) * 56 + hb * 7 + hh) * 56 + wq * 7 + ww2;
}

// ---------------- f32 -> bf16 bulk convert ----------------
__global__ __launch_bounds__(256) void conv_kernel(
    const float* __restrict__ src, unsigned short* __restrict__ dst, int n4)
{
    int stride = gridDim.x * 256;
    for (int i = blockIdx.x * 256 + threadIdx.x; i < n4; i += stride) {
        float4 v = *reinterpret_cast<const float4*>(&src[(size_t)i * 4]);
        short4 o;
        o.x = (short)f2bf(v.x); o.y = (short)f2bf(v.y);
        o.z = (short)f2bf(v.z); o.w = (short)f2bf(v.w);
        *reinterpret_cast<short4*>(&dst[(size_t)i * 4]) = o;
    }
}

// 4 weight tensors in one dispatch (vec4 counts)
__global__ __launch_bounds__(256) void conv4_kernel(
    const float* __restrict__ s0, unsigned short* __restrict__ d0, int n0,
    const float* __restrict__ s1, unsigned short* __restrict__ d1, int n1,
    const float* __restrict__ s2, unsigned short* __restrict__ d2, int n2,
    const float* __restrict__ s3, unsigned short* __restrict__ d3, int n3)
{
    int stride = gridDim.x * 256;
    int total = n0 + n1 + n2 + n3;
    for (int i = blockIdx.x * 256 + threadIdx.x; i < total; i += stride) {
        const float* s; unsigned short* d; int j = i;
        if (j < n0) { s = s0; d = d0; }
        else if ((j -= n0) < n1) { s = s1; d = d1; }
        else if ((j -= n1) < n2) { s = s2; d = d2; }
        else { j -= n2; s = s3; d = d3; }
        float4 v = *reinterpret_cast<const float4*>(&s[(size_t)j * 4]);
        short4 o;
        o.x = (short)f2bf(v.x); o.y = (short)f2bf(v.y);
        o.z = (short)f2bf(v.z); o.w = (short)f2bf(v.w);
        *reinterpret_cast<short4*>(&d[(size_t)j * 4]) = o;
    }
}

// ---------------- prep stage 1: CPB-MLP table, one block per table row ----------------
__global__ __launch_bounds__(256) void prep_table_kernel(
    const float* __restrict__ w1, const float* __restrict__ b1,
    const float* __restrict__ w2, const float* __restrict__ tabin,
    float* __restrict__ tableg)
{
    const int i = blockIdx.x;          // 0..168
    const int t = threadIdx.x;
    const float c0 = tabin[i * 3], c1 = tabin[i * 3 + 1], c2 = tabin[i * 3 + 2];
    float part[8] = {0.f, 0.f, 0.f, 0.f, 0.f, 0.f, 0.f, 0.f};
    for (int j = t; j < 512; j += 256) {
        float hv = fmaxf(c0 * w1[j * 3] + c1 * w1[j * 3 + 1] + c2 * w1[j * 3 + 2] + b1[j], 0.f);
        #pragma unroll
        for (int h = 0; h < 8; ++h) part[h] += hv * w2[h * 512 + j];
    }
    #pragma unroll
    for (int h = 0; h < 8; ++h) {
        float v = part[h];
        v += __shfl_xor(v, 1);  v += __shfl_xor(v, 2);  v += __shfl_xor(v, 4);
        v += __shfl_xor(v, 8);  v += __shfl_xor(v, 16); v += __shfl_xor(v, 32);
        part[h] = v;
    }
    __shared__ float red[4][8];
    const int wv = t >> 6, lane = t & 63;
    if (lane == 0) {
        #pragma unroll
        for (int h = 0; h < 8; ++h) red[wv][h] = part[h];
    }
    __syncthreads();
    if (t < 8) tableg[i * 8 + t] = red[0][t] + red[1][t] + red[2][t] + red[3][t];
}

// ---------------- prep stage 2: scales, qkv bias, rpbf expansion ----------------
// rpbf layout [h][mi][ji][r16][g4][r] = rpb[i][j] with i = mi*16 + r16,
// j = ji*16 + g4*4 + r  (matches swapped-QK S^T fragment orientation).
__global__ __launch_bounds__(256) void prep_expand_kernel(
    const float* __restrict__ logit_scale,
    const float* __restrict__ qb, const float* __restrict__ vb,
    const int* __restrict__ rpi, const float* __restrict__ tableg,
    float* __restrict__ scales, float* __restrict__ rpbf,
    float* __restrict__ qkvb)
{
    const int stride = gridDim.x * 256;
    const int gt = blockIdx.x * 256 + threadIdx.x;
    if (gt < 8) scales[gt] = expf(fminf(logit_scale[gt], 4.6051702f)); // ln(100)
    for (int i = gt; i < 768; i += stride) {
        float o;
        if (i < 256) o = qb[i];
        else if (i < 512) o = 0.f;
        else o = vb[i - 512];
        qkvb[i] = o;
    }
    for (int e = gt; e < 32768; e += stride) {
        int h = e >> 12, rem = e & 4095;
        int mi = rem >> 10, ji = (rem >> 8) & 3;
        int r16 = (rem >> 4) & 15, g4 = (rem >> 2) & 3, r = rem & 3;
        int i = mi * 16 + r16, j = ji * 16 + g4 * 4 + r;   // swapped orientation
        float val = 0.f;
        if (i < 49 && j < 49) {
            float xv = tableg[rpi[i * 49 + j] * 8 + h];
            val = 16.f / (1.f + expf(-xv));
        }
        rpbf[e] = val;
    }
}

// ---------------- GEMM: 128x128 tile, 8 waves x (64x32), 3-buffer pipeline ----------------
template<int ACT>
__global__ __launch_bounds__(512, 6) void gemm2_kernel(
    const unsigned short* __restrict__ A, const unsigned short* __restrict__ W,
    const float* __restrict__ bias, unsigned short* __restrict__ C,
    int M, int N, int K, int ntn)
{
    __shared__ unsigned short smem[24576];   // 48KB: 3 x (As 128x32 + Bs 128x32)
    const int tid = threadIdx.x;
    const int lane = tid & 63, wv = tid >> 6;
    const int wr = wv >> 2, wc = wv & 3;
    const int nwg = gridDim.x;
    const int virt = (blockIdx.x & 7) * (nwg >> 3) + (blockIdx.x >> 3);
    const int bn = virt % ntn, bm = virt / ntn;
    const size_t arow0 = (size_t)bm * 128;
    const size_t brow0 = (size_t)bn * 128;
    const int r16 = lane & 15, g4 = lane >> 4;
    const int srow_l = lane >> 2;
    const int sgran  = (lane & 3) ^ ((srow_l >> 1) & 3);
    f32x4 acc[4][2] = {};

    auto STAGE = [&](int buf, int kt) {      // 2 loads per thread
        unsigned short* As = smem + buf * 8192;
        unsigned short* Bs = As + 4096;
        int row0 = wv * 16;
        async16(&A[(arow0 + row0 + srow_l) * (size_t)K + kt + sgran * 8], &As[row0 * 32]);
        async16(&W[(brow0 + row0 + srow_l) * (size_t)K + kt + sgran * 8], &Bs[row0 * 32]);
    };
    auto COMPUTE = [&](int buf) {
        unsigned short* As = smem + buf * 8192;
        unsigned short* Bs = As + 4096;
        short8_t af[4], bfr[2];
        const int gsw = g4 ^ ((r16 >> 1) & 3);
        #pragma unroll
        for (int m = 0; m < 4; ++m) {
            int row = wr * 64 + m * 16 + r16;
            af[m] = *reinterpret_cast<const short8_t*>(&As[row * 32 + gsw * 8]);
        }
        #pragma unroll
        for (int n = 0; n < 2; ++n) {
            int row = wc * 32 + n * 16 + r16;
            bfr[n] = *reinterpret_cast<const short8_t*>(&Bs[row * 32 + gsw * 8]);
        }
        #pragma unroll
        for (int m = 0; m < 4; ++m)
            #pragma unroll
            for (int n = 0; n < 2; ++n)
                acc[m][n] = __builtin_amdgcn_mfma_f32_16x16x32_bf16(af[m], bfr[n], acc[m][n], 0, 0, 0);
    };

    const int nk = K >> 5;
    STAGE(0, 0);
    STAGE(1, 32);
    int cb = 0;
    for (int ks = 0; ks < nk; ++ks) {
        if (ks == nk - 1) { asm volatile("s_waitcnt vmcnt(0)" ::: "memory"); }
        else              { asm volatile("s_waitcnt vmcnt(2)" ::: "memory"); }
        __builtin_amdgcn_sched_barrier(0);
        asm volatile("s_barrier" ::: "memory");
        if (ks + 2 < nk) {
            int sb = cb + 2; if (sb >= 3) sb -= 3;
            STAGE(sb, (ks + 2) << 5);
        }
        __builtin_amdgcn_sched_barrier(0);
        COMPUTE(cb);
        cb = (cb == 2) ? 0 : cb + 1;
    }
    __builtin_amdgcn_sched_barrier(0);
    asm volatile("s_barrier" ::: "memory");  // LDS dead; epilogue overlays

    // ---- epilogue: per-wave 64x36 transpose -> coalesced stores ----
    unsigned short* Cs = smem + wv * 2304;   // 64 x 36 ushorts per wave
    const int rbase = g4 * 4;
    const int srow = lane >> 2, scol = (lane & 3) * 8;
    const int gcol0 = bn * 128 + wc * 32;
    #pragma unroll
    for (int n = 0; n < 2; ++n) {
        float bv = bias[gcol0 + n * 16 + r16];
        #pragma unroll
        for (int m = 0; m < 4; ++m)
            #pragma unroll
            for (int r = 0; r < 4; ++r) {
                float v = acc[m][n][r] + bv;
                if (ACT == 1) v = fast_gelu(v);
                Cs[(m * 16 + rbase + r) * 36 + n * 16 + r16] = f2bf(v);
            }
    }
    #pragma unroll
    for (int pass = 0; pass < 4; ++pass) {
        int lr = pass * 16 + srow;
        int grow = bm * 128 + wr * 64 + lr;
        short8_t vv = *reinterpret_cast<const short8_t*>(&Cs[lr * 36 + scol]);
        *reinterpret_cast<short8_t*>(&C[(size_t)grow * N + gcol0 + scol]) = vv;
    }
}

// ---------------- fused GEMM + residual + LayerNorm (N=256), 2-buffer 48KB ----------
// 2-buffer counted-vmcnt (r13 structure) -> 48KB LDS -> 3 blocks/CU (was 2 at 72KB):
// 784-block grids fit in ~one residency round (tail-quantization fix).
template<int SCATTER, int OUT_F32>
__global__ __launch_bounds__(512) void gemm_ln_kernel(
    const unsigned short* __restrict__ A, const unsigned short* __restrict__ W,
    const float* __restrict__ bias, const unsigned short* __restrict__ resid,
    const float* __restrict__ gamma, const float* __restrict__ beta,
    void* __restrict__ Cv, int M, int K)
{
    __shared__ unsigned short smem[24576];   // 48KB: 2 x (As 8KB + Bs 16KB)
    const int tid = threadIdx.x;
    const int lane = tid & 63, wv = tid >> 6;
    const int wr = wv >> 2, wc = wv & 3;
    const int nwg = gridDim.x;
    const int bm = (blockIdx.x & 7) * (nwg >> 3) + (blockIdx.x >> 3);
    const size_t arow0 = (size_t)bm * 128;
    const int r16 = lane & 15, g4 = lane >> 4;
    const int srow_l = lane >> 2;
    const int sgran = (lane & 3) ^ ((srow_l >> 1) & 3);
    f32x4 acc[4][4] = {};

    auto STAGE = [&](int buf, int kt) {      // 3 loads per thread
        unsigned short* As = smem + buf * 12288;
        unsigned short* Bs = As + 4096;
        async16(&A[(arow0 + wv * 16 + srow_l) * (size_t)K + kt + sgran * 8],
                &As[(wv * 16) * 32]);
        #pragma unroll
        for (int i = 0; i < 2; ++i) {
            int row0 = wv * 32 + i * 16;
            async16(&W[(size_t)(row0 + srow_l) * K + kt + sgran * 8], &Bs[row0 * 32]);
        }
    };
    auto COMPUTE = [&](int buf) {
        unsigned short* As = smem + buf * 12288;
        unsigned short* Bs = As + 4096;
        short8_t af[4], bfr[4];
        const int gsw = g4 ^ ((r16 >> 1) & 3);
        #pragma unroll
        for (int m = 0; m < 4; ++m) {
            int row = wr * 64 + m * 16 + r16;
            af[m] = *reinterpret_cast<const short8_t*>(&As[row * 32 + gsw * 8]);
        }
        #pragma unroll
        for (int n = 0; n < 4; ++n) {
            int row = wc * 64 + n * 16 + r16;
            bfr[n] = *reinterpret_cast<const short8_t*>(&Bs[row * 32 + gsw * 8]);
        }
        #pragma unroll
        for (int m = 0; m < 4; ++m)
            #pragma unroll
            for (int n = 0; n < 4; ++n)
                acc[m][n] = __builtin_amdgcn_mfma_f32_16x16x32_bf16(af[m], bfr[n], acc[m][n], 0, 0, 0);
    };

    const int nk = K >> 5;
    STAGE(0, 0);
    STAGE(1, 32);
    int cur = 0;
    for (int ks = 0; ks < nk; ++ks) {
        if (ks == nk - 1) { asm volatile("s_waitcnt vmcnt(0)" ::: "memory"); }
        else              { asm volatile("s_waitcnt vmcnt(3)" ::: "memory"); }
        __builtin_amdgcn_sched_barrier(0);
        asm volatile("s_barrier" ::: "memory");      // buf cur fully populated
        COMPUTE(cur);
        __builtin_amdgcn_sched_barrier(0);
        asm volatile("s_barrier" ::: "memory");      // all reads of buf cur done
        if (ks + 2 < nk) STAGE(cur, (ks + 2) << 5);  // restage 2 ahead
        cur ^= 1;
    }
    // final in-loop barrier already drained LDS reads; epilogue overlays buffers

    float bv[4];
    #pragma unroll
    for (int n = 0; n < 4; ++n) bv[n] = bias[wc * 64 + n * 16 + r16];
    float* psum  = reinterpret_cast<float*>(smem + 19456);   // byte 38912: [128][4]
    float* psq   = psum + 512;                               // [128][4]
    float* stats = psq + 512;                                // [128][2]
    #pragma unroll
    for (int m = 0; m < 4; ++m) {
        #pragma unroll
        for (int r = 0; r < 4; ++r) {
            float s = 0.f, s2 = 0.f;
            #pragma unroll
            for (int n = 0; n < 4; ++n) {
                float v = acc[m][n][r] + bv[n];
                s += v; s2 += v * v;
            }
            s  += __shfl_xor(s, 1);  s  += __shfl_xor(s, 2);
            s  += __shfl_xor(s, 4);  s  += __shfl_xor(s, 8);
            s2 += __shfl_xor(s2, 1); s2 += __shfl_xor(s2, 2);
            s2 += __shfl_xor(s2, 4); s2 += __shfl_xor(s2, 8);
            if (r16 == 0) {
                int row = wr * 64 + m * 16 + g4 * 4 + r;
                psum[row * 4 + wc] = s;
                psq[row * 4 + wc]  = s2;
            }
        }
    }
    __syncthreads();
    if (tid < 128) {
        f32x4 a = *reinterpret_cast<const f32x4*>(&psum[tid * 4]);
        f32x4 b = *reinterpret_cast<const f32x4*>(&psq[tid * 4]);
        float mu  = (a[0] + a[1] + a[2] + a[3]) * 0.00390625f;
        float ex2 = (b[0] + b[1] + b[2] + b[3]) * 0.00390625f;
        stats[tid * 2]     = mu;
        stats[tid * 2 + 1] = rsqrtf(ex2 - mu * mu + 1e-5f);
    }
    __syncthreads();

    unsigned short* Cs = smem + wv * 2432;   // 32 x 76 ushorts per wave (< 19456)
    const int rbase = g4 * 4;
    const int srow = lane >> 3, scol = (lane & 7) * 8;
    const int gcol0 = wc * 64;
    f32x4 gm0 = *reinterpret_cast<const f32x4*>(&gamma[gcol0 + scol]);
    f32x4 gm1 = *reinterpret_cast<const f32x4*>(&gamma[gcol0 + scol + 4]);
    f32x4 bt0 = *reinterpret_cast<const f32x4*>(&beta[gcol0 + scol]);
    f32x4 bt1 = *reinterpret_cast<const f32x4*>(&beta[gcol0 + scol + 4]);
    #pragma unroll
    for (int p = 0; p < 2; ++p) {
        #pragma unroll
        for (int n = 0; n < 4; ++n)
            #pragma unroll
            for (int m2 = 0; m2 < 2; ++m2)
                #pragma unroll
                for (int r = 0; r < 4; ++r)
                    Cs[(m2 * 16 + rbase + r) * 76 + n * 16 + r16] =
                        f2bf(acc[p * 2 + m2][n][r] + bv[n]);
        #pragma unroll
        for (int rr = 0; rr < 4; ++rr) {
            int lr = rr * 8 + srow;
            int lrow = wr * 64 + p * 32 + lr;
            int grow = bm * 128 + lrow;
            size_t orow = SCATTER ? (size_t)win_row_to_token(grow) : (size_t)grow;
            float mu  = stats[lrow * 2];
            float inv = stats[lrow * 2 + 1];
            short8_t cv = *reinterpret_cast<const short8_t*>(&Cs[lr * 76 + scol]);
            short8_t rv = *reinterpret_cast<const short8_t*>(&resid[orow * 256 + gcol0 + scol]);
            float o[8];
            #pragma unroll
            for (int e = 0; e < 8; ++e) {
                float g = (e < 4) ? gm0[e] : gm1[e - 4];
                float bb = (e < 4) ? bt0[e] : bt1[e - 4];
                o[e] = bf2f((unsigned short)rv[e])
                     + (bf2f((unsigned short)cv[e]) - mu) * inv * g + bb;
            }
            if (OUT_F32) {
                float* outp = (float*)Cv + orow * 256 + gcol0 + scol;
                f32x4 o0, o1;
                #pragma unroll
                for (int e = 0; e < 4; ++e) { o0[e] = o[e]; o1[e] = o[e + 4]; }
                *reinterpret_cast<f32x4*>(outp)     = o0;
                *reinterpret_cast<f32x4*>(outp + 4) = o1;
            } else {
                unsigned short* outp = (unsigned short*)Cv + orow * 256 + gcol0 + scol;
                short8_t ov;
                #pragma unroll
                for (int e = 0; e < 8; ++e) ov[e] = (short)f2bf(o[e]);
                *reinterpret_cast<short8_t*>(outp) = ov;
            }
        }
    }
}

// ---------------- attention: TWO (window,head) pairs per 128-thread block ----------------
__global__ __launch_bounds__(128) void attn_kernel(
    const unsigned short* __restrict__ qkv, const float* __restrict__ scales,
    const float* __restrict__ rpbf, unsigned short* __restrict__ out)
{
    constexpr int PO = 0;        // 64 x 72 ushorts
    constexpr int VO = 4608;     // 32 x 72 ushorts
    __shared__ unsigned short lds_all[13824];   // 2 x 6912 ushorts

    const int wv = threadIdx.x >> 6;
    const int lane = threadIdx.x & 63;
    unsigned short* lds = lds_all + wv * 6912;

    const int pair = blockIdx.x * 2 + wv;
    const int h = pair & 7, wb = pair >> 3;
    const int r16 = lane & 15, g4 = lane >> 4;

    const int wq = wb & 7, hb = (wb >> 3) & 7, dd = (wb >> 6) & 7, bb2 = wb >> 9;
    const int tok_base = ((bb2 * 8 + dd) * 56 + hb * 7) * 56 + wq * 7;
    const float sc = scales[h];

    // zero V^T j-pad (j 48..63)
    {
        short8_t z = {};
        int d = lane >> 1, j0 = 48 + (lane & 1) * 8;
        *reinterpret_cast<short8_t*>(&lds[VO + d * 72 + j0]) = z;
    }
    // stage V^T via register transpose: short8 row loads -> 8 scalar LDS writes
    for (int c = lane; c < 196; c += 64) {
        int j = c >> 2, gi = c & 3;
        int tok = tok_base + (j / 7) * 56 + (j % 7);
        short8_t raw = *reinterpret_cast<const short8_t*>(
            qkv + (size_t)tok * 768 + 512 + h * 32 + gi * 8);
        #pragma unroll
        for (int e = 0; e < 8; ++e)
            lds[VO + (gi * 8 + e) * 72 + j] = (unsigned short)raw[e];
    }

    // Q/K fragments: direct global load + cross-lane l2norm
    short8_t qf[4], kf[4];
    #pragma unroll
    for (int sel = 0; sel < 2; ++sel) {
        #pragma unroll
        for (int mi = 0; mi < 4; ++mi) {
            int row = mi * 16 + r16;
            int tok = tok_base + (row / 7) * 56 + (row % 7);
            short8_t raw = *reinterpret_cast<const short8_t*>(
                qkv + (size_t)tok * 768 + sel * 256 + h * 32 + g4 * 8);
            float f[8]; float ss = 0.f;
            #pragma unroll
            for (int e = 0; e < 8; ++e) { f[e] = bf2f((unsigned short)raw[e]); ss += f[e] * f[e]; }
            ss += __shfl_xor(ss, 16); ss += __shfl_xor(ss, 32);
            float inv = 1.f / fmaxf(sqrtf(ss), 1e-12f);
            if (sel == 0) inv *= sc;
            short8_t o;
            #pragma unroll
            for (int e = 0; e < 8; ++e) o[e] = (short)f2bf(f[e] * inv);
            if (sel == 0) qf[mi] = o; else kf[mi] = o;
        }
    }
    __syncthreads();   // V^T staged (both waves; equal-length work)

    // ---- QK^T swapped: accT[ji][mi] = K_tile(ji) x Q_tile(mi)^T ----
    f32x4 accT[4][4] = {};
    __builtin_amdgcn_s_setprio(1);
    #pragma unroll
    for (int ji = 0; ji < 4; ++ji)
        #pragma unroll
        for (int mi = 0; mi < 4; ++mi)
            accT[ji][mi] = __builtin_amdgcn_mfma_f32_16x16x32_bf16(kf[ji], qf[mi], accT[ji][mi], 0, 0, 0);
    __builtin_amdgcn_s_setprio(0);

    // ---- prefetch rpb fragments (layout matches: [mi][ji][r16][g4][r]) ----
    const float* rbf = rpbf + h * 4096 + r16 * 16 + g4 * 4;
    f32x4 rbv[4][4];
    #pragma unroll
    for (int mi = 0; mi < 4; ++mi)
        #pragma unroll
        for (int ji = 0; ji < 4; ++ji)
            rbv[mi][ji] = *reinterpret_cast<const f32x4*>(&rbf[(mi * 4 + ji) * 256]);

    // ---- softmax over j (lane-local + 2 shfls), P -> LDS bf16 [i][j] ----
    #pragma unroll
    for (int mi = 0; mi < 4; ++mi) {
        const int i = mi * 16 + r16;
        float m = -1e30f;
        #pragma unroll
        for (int ji = 0; ji < 4; ++ji)
            #pragma unroll
            for (int r = 0; r < 4; ++r) {
                int j = ji * 16 + (g4 << 2) + r;
                float v = accT[ji][mi][r] + rbv[mi][ji][r];
                v = (j < 49) ? v : -1e30f;
                accT[ji][mi][r] = v;
                m = fmaxf(m, v);
            }
        m = fmaxf(m, __shfl_xor(m, 16));
        m = fmaxf(m, __shfl_xor(m, 32));
        float sum = 0.f;
        #pragma unroll
        for (int ji = 0; ji < 4; ++ji)
            #pragma unroll
            for (int r = 0; r < 4; ++r) {
                float v = accT[ji][mi][r];
                float e = (v > -1e29f) ? __expf(v - m) : 0.f;
                accT[ji][mi][r] = e;
                sum += e;
            }
        sum += __shfl_xor(sum, 16);
        sum += __shfl_xor(sum, 32);
        float rinv = 1.f / sum;
        #pragma unroll
        for (int ji = 0; ji < 4; ++ji)
            #pragma unroll
            for (int r = 0; r < 4; ++r)
                lds[PO + i * 72 + ji * 16 + (g4 << 2) + r] = f2bf(accT[ji][mi][r] * rinv);
    }
    __syncthreads();   // P writes drained before ds_read

    // ---- PV: setprio(1) cluster (P[i][j], V^T[d][j]) ----
    f32x4 acc2[4][2] = {};
    __builtin_amdgcn_s_setprio(1);
    #pragma unroll
    for (int ks = 0; ks < 2; ++ks) {
        short8_t pf[4], vf[2];
        int ko = ks * 32 + g4 * 8;
        #pragma unroll
        for (int mi = 0; mi < 4; ++mi)
            pf[mi] = *reinterpret_cast<const short8_t*>(&lds[PO + (mi * 16 + r16) * 72 + ko]);
        #pragma unroll
        for (int ni = 0; ni < 2; ++ni)
            vf[ni] = *reinterpret_cast<const short8_t*>(&lds[VO + (ni * 16 + r16) * 72 + ko]);
        #pragma unroll
        for (int mi = 0; mi < 4; ++mi)
            #pragma unroll
            for (int ni = 0; ni < 2; ++ni)
                acc2[mi][ni] = __builtin_amdgcn_mfma_f32_16x16x32_bf16(pf[mi], vf[ni], acc2[mi][ni], 0, 0, 0);
    }
    __builtin_amdgcn_s_setprio(0);

    #pragma unroll
    for (int mi = 0; mi < 4; ++mi)
        #pragma unroll
        for (int r = 0; r < 4; ++r) {
            int i = mi * 16 + g4 * 4 + r;
            if (i < 49) {
                size_t ob = (size_t)(wb * 49 + i) * 256 + h * 32;
                out[ob + r16]      = f2bf(acc2[mi][0][r]);
                out[ob + 16 + r16] = f2bf(acc2[mi][1][r]);
            }
        }
}

extern "C" void kernel_launch(void* const* d_in, const int* in_sizes, int n_in,
                              void* d_out, int out_size, void* d_ws, size_t ws_size,
                              hipStream_t stream) {
    const float* x      = (const float*)d_in[0];
    const float* qkv_w  = (const float*)d_in[1];
    const float* q_bias = (const float*)d_in[2];
    const float* v_bias = (const float*)d_in[3];
    const float* lscale = (const float*)d_in[4];
    const float* cpb_w1 = (const float*)d_in[5];
    const float* cpb_b1 = (const float*)d_in[6];
    const float* cpb_w2 = (const float*)d_in[7];
    const float* proj_w = (const float*)d_in[8];
    const float* proj_b = (const float*)d_in[9];
    const float* n1g    = (const float*)d_in[10];
    const float* n1b    = (const float*)d_in[11];
    const float* fc1_w  = (const float*)d_in[12];
    const float* fc1_b  = (const float*)d_in[13];
    const float* fc2_w  = (const float*)d_in[14];
    const float* fc2_b  = (const float*)d_in[15];
    const float* n2g    = (const float*)d_in[16];
    const float* n2b    = (const float*)d_in[17];
    const float* rct    = (const float*)d_in[18];
    const int*   rpi    = (const int*)d_in[19];

    char* ws = (char*)d_ws;
    unsigned short* qkv    = (unsigned short*)(ws);
    unsigned short* hbuf   = (unsigned short*)(ws);
    unsigned short* attn_o = (unsigned short*)(ws + 154140672);
    unsigned short* xb     = (unsigned short*)(ws + 205520896);
    unsigned short* x1     = (unsigned short*)(ws + 205520896);
    unsigned short* wqkv   = (unsigned short*)(ws + 308281344);
    unsigned short* wproj  = (unsigned short*)(ws + 308674560);
    unsigned short* wfc1   = (unsigned short*)(ws + 308805632);
    unsigned short* wfc2   = (unsigned short*)(ws + 309329920);
    float*          rpbf   = (float*)(ws + 309854208);
    float*          scales = (float*)(ws + 310378496);
    float*          qkvb   = (float*)(ws + 310378528);
    float*          tableg = (float*)(ws + 310381600);

    const int M = 100352;

    conv_kernel<<<2048, 256, 0, stream>>>(x, xb, 25690112 / 4);
    conv4_kernel<<<768, 256, 0, stream>>>(qkv_w, wqkv, 49152,
                                          proj_w, wproj, 16384,
                                          fc1_w, wfc1, 65536,
                                          fc2_w, wfc2, 65536);
    prep_table_kernel<<<169, 256, 0, stream>>>(cpb_w1, cpb_b1, cpb_w2, rct, tableg);
    prep_expand_kernel<<<128, 256, 0, stream>>>(lscale, q_bias, v_bias, rpi, tableg,
                                                scales, rpbf, qkvb);
    // qkv = xb @ wqkv^T + qkv_bias   (128x128 tiles: 784 x 6)
    gemm2_kernel<0><<<4704, 512, 0, stream>>>(xb, wqkv, qkvb, qkv, M, 768, 256, 6);
    // attention: 2 (window,head) pairs per block -> window-ordered (Bw*49, 256)
    attn_kernel<<<8192, 128, 0, stream>>>(qkv, scales, rpbf, attn_o);
    // x1 = xb + LN(attn_o @ wproj^T + proj_b)  [fused, scatter to natural order]
    gemm_ln_kernel<1, 0><<<784, 512, 0, stream>>>(attn_o, wproj, proj_b, xb, n1g, n1b,
                                                  x1, M, 256);
    // h = gelu(x1 @ wfc1^T + fc1_b)   (128x128 tiles: 784 x 8)
    gemm2_kernel<1><<<6272, 512, 0, stream>>>(x1, wfc1, fc1_b, hbuf, M, 1024, 256, 8);
    // out = x1 + LN(h @ wfc2^T + fc2_b)  [fused, f32 output]
    gemm_ln_kernel<0, 1><<<784, 512, 0, stream>>>(hbuf, wfc2, fc2_b, x1, n2g, n2b,
                                                  d_out, M, 1024);
}